// Round 11
// baseline (292.502 us; speedup 1.0000x reference)
//
#include <hip/hip_runtime.h>
#include <hip/hip_bf16.h>

#define HID 64
#define IN_EMB 128
#define IN_DIM 130
#define ROWS_PER_BKT 512      // coarse buckets: 100000/512 -> 196 buckets
#define LOG_RPB 9
#define MAX_BKT 256           // >= nbkt (196)
#define PART_CHUNK 4096       // edges per partition block (782 blocks)
#define SLOT_E 18432          // fixed tmp slot per bucket (mean 16384, sd 128 -> 16 sigma)
#define W1TS 160              // W1T row stride (k entries, zero-padded past 130)
#define RPB 32                // rows per spmm block (one row per 8-lane subgroup)
#define ECAP 2048             // staged edges per spmm block (16KB LDS); avg 1024

typedef __hip_bfloat16 bf16;
typedef __attribute__((ext_vector_type(8))) short bf16x8;
typedef __attribute__((ext_vector_type(4))) float fx4;
typedef __attribute__((ext_vector_type(2))) float fx2;

__device__ __forceinline__ short f2bfs(float f) {
  __hip_bfloat16 h = __float2bfloat16(f);
  return *(reinterpret_cast<short*>(&h));
}
// pack 4 floats -> 4 fp8 e4m3 bytes (HW cvt)
__device__ __forceinline__ int pk_fp8x4(float a, float b, float c, float d) {
  int v = __builtin_amdgcn_cvt_pk_fp8_f32(a, b, 0, false);
  v = __builtin_amdgcn_cvt_pk_fp8_f32(c, d, v, true);
  return v;
}
__device__ __forceinline__ unsigned char f2fp8(float x) {
  return (unsigned char)(__builtin_amdgcn_cvt_pk_fp8_f32(x, x, 0, false) & 0xFF);
}

// ---------------- weight transpose prep: W1T[c][k], W2T[c][k] (bf16) ---------
// W1T: 64 x W1TS (k zero-padded past IN_DIM); W2T: 64 x 64.
// Fragments become contiguous 16B loads; tables L1-resident (20.5KB + 8KB).
__global__ __launch_bounds__(256) void wprep_kernel(
    const float* __restrict__ W1, const float* __restrict__ W2,
    short* __restrict__ w1t, short* __restrict__ w2t) {
  const int t = threadIdx.x;
  if (blockIdx.x == 0) {
    for (int idx = t; idx < 64 * W1TS; idx += 256) {
      int c = idx / W1TS, k = idx % W1TS;
      w1t[idx] = f2bfs((k < IN_DIM) ? W1[k * HID + c] : 0.f);
    }
  } else {
    for (int idx = t; idx < 64 * 64; idx += 256) {
      int c = idx >> 6, k = idx & 63;
      w2t[idx] = f2bfs(W2[k * HID + c]);
    }
  }
}

// ---------------- exclusive scan of bucket counts (1 block) ------------------
__global__ __launch_bounds__(1024) void bscan_kernel(const int* __restrict__ bcnt,
                                                     int* __restrict__ bstart,
                                                     int* __restrict__ row_ptr,
                                                     int n, int nbkt) {
  __shared__ int s[1024];
  const int t = threadIdx.x;
  const int v = (t < nbkt) ? bcnt[t] : 0;
  s[t] = v;
  __syncthreads();
  for (int off = 1; off < 1024; off <<= 1) {
    int u = (t >= off) ? s[t - off] : 0;
    __syncthreads();
    s[t] += u;
    __syncthreads();
  }
  if (t < nbkt) bstart[t] = s[t] - v;
  if (t == 0) { bstart[nbkt] = s[1023]; row_ptr[n] = s[1023]; }   // == nE
}

// ---------------- partition: LDS-reordered scatter (coalesced stores) --------
__global__ __launch_bounds__(512) void partition_kernel(
    const int* __restrict__ row, const int* __restrict__ col,
    const float* __restrict__ vals, int* __restrict__ bcur,
    int2* __restrict__ tmp, int nE) {
  __shared__ int2 lbuf[PART_CHUNK];            // 32 KB
  __shared__ unsigned char lbid[PART_CHUNK];   // 4 KB: bucket id per slot
  __shared__ int h[MAX_BKT];
  __shared__ int sc[MAX_BKT];
  __shared__ int lofs[MAX_BKT + 1];
  __shared__ int lcur[MAX_BKT];
  __shared__ int gbase[MAX_BKT];
  const int t = threadIdx.x;
  const int base = blockIdx.x * PART_CHUNK;    // multiple of 4096
  const int cntE = min(PART_CHUNK, nE - base);

  if (t < MAX_BKT) h[t] = 0;
  __syncthreads();
  // phase 1: histogram
  for (int kk = t; kk < PART_CHUNK / 4; kk += 512) {
    int e0 = base + kk * 4;
    if (e0 + 3 < nE) {
      int4 r4 = ((const int4*)row)[(base >> 2) + kk];
      atomicAdd(&h[r4.x >> LOG_RPB], 1);
      atomicAdd(&h[r4.y >> LOG_RPB], 1);
      atomicAdd(&h[r4.z >> LOG_RPB], 1);
      atomicAdd(&h[r4.w >> LOG_RPB], 1);
    } else {
      for (int j = 0; j < 4; ++j) {
        int e = e0 + j;
        if (e < nE) atomicAdd(&h[row[e] >> LOG_RPB], 1);
      }
    }
  }
  __syncthreads();
  // phase 2: exclusive prefix + global reservation
  if (t < MAX_BKT) sc[t] = h[t];
  __syncthreads();
  for (int off = 1; off < MAX_BKT; off <<= 1) {
    int u = (t < MAX_BKT && t >= off) ? sc[t - off] : 0;
    __syncthreads();
    if (t < MAX_BKT) sc[t] += u;
    __syncthreads();
  }
  if (t < MAX_BKT) {
    int ex = sc[t] - h[t];
    lofs[t] = ex;
    lcur[t] = ex;
    if (h[t] > 0) gbase[t] = t * SLOT_E + atomicAdd(&bcur[t], h[t]);
  }
  if (t == MAX_BKT - 1) lofs[MAX_BKT] = sc[t];   // == cntE
  __syncthreads();
  // phase 3: scatter into bucket-major LDS buffer
  for (int kk = t; kk < PART_CHUNK / 4; kk += 512) {
    int e0 = base + kk * 4;
    if (e0 + 3 < nE) {
      int4 r4 = ((const int4*)row)[(base >> 2) + kk];
      int4 c4 = ((const int4*)col)[(base >> 2) + kk];
      float4 v4 = ((const float4*)vals)[(base >> 2) + kk];
      int rr[4] = {r4.x, r4.y, r4.z, r4.w};
      int cc[4] = {c4.x, c4.y, c4.z, c4.w};
      float vv[4] = {v4.x, v4.y, v4.z, v4.w};
#pragma unroll
      for (int j = 0; j < 4; ++j) {
        int b = rr[j] >> LOG_RPB;
        int p = atomicAdd(&lcur[b], 1);
        lbuf[p] = make_int2(cc[j] | ((rr[j] & (ROWS_PER_BKT - 1)) << 20),
                            __float_as_int(vv[j]));
        lbid[p] = (unsigned char)b;
      }
    } else {
      for (int j = 0; j < 4; ++j) {
        int e = e0 + j;
        if (e < nE) {
          int r = row[e];
          int b = r >> LOG_RPB;
          int p = atomicAdd(&lcur[b], 1);
          lbuf[p] = make_int2(col[e] | ((r & (ROWS_PER_BKT - 1)) << 20),
                              __float_as_int(vals[e]));
          lbid[p] = (unsigned char)b;
        }
      }
    }
  }
  __syncthreads();
  // phase 4: coalesced copy-out
  for (int i = t; i < cntE; i += 512) {
    int b = lbid[i];
    int off = i - lofs[b];
    int g = gbase[b] + off;
    if (g - b * SLOT_E < SLOT_E) tmp[g] = lbuf[i];
  }
}

// ---------------- per-bucket counting sort (two-pass, slim LDS) --------------
__global__ __launch_bounds__(512) void bucket_sort_kernel(
    const int* __restrict__ bstart, const int2* __restrict__ tmp,
    int2* __restrict__ ce, int* __restrict__ row_ptr, int n) {
  __shared__ int rcnt[ROWS_PER_BKT];
  __shared__ int rpos[ROWS_PER_BKT];
  __shared__ int sc[ROWS_PER_BKT];
  const int t = threadIdx.x;
  const int b = blockIdx.x;
  const int start = bstart[b];
  const int len   = bstart[b + 1] - start;
  const int2* ts = tmp + (size_t)b * SLOT_E;
  rcnt[t] = 0;
  __syncthreads();
  const int* keys = (const int*)ts;              // ts[i].x at index 2*i
  for (int i = t; i < len; i += 512)
    atomicAdd(&rcnt[((unsigned)keys[2 * i]) >> 20], 1);
  __syncthreads();
  sc[t] = rcnt[t];
  __syncthreads();
  for (int off = 1; off < ROWS_PER_BKT; off <<= 1) {
    int u = (t >= off) ? sc[t - off] : 0;
    __syncthreads();
    sc[t] += u;
    __syncthreads();
  }
  {
    int ex = sc[t] - rcnt[t];
    int gpos = start + ex;
    rpos[t] = gpos;
    int gr = b * ROWS_PER_BKT + t;
    if (gr < n) row_ptr[gr] = gpos;
  }
  __syncthreads();
  for (int i = t; i < len; i += 512) {
    int2 e = ts[i];
    int p = atomicAdd(&rpos[((unsigned)e.x) >> 20], 1);
    ce[p] = make_int2(e.x & 0xFFFFF, e.y);
  }
}

// ---------------- Linear1 via MFMA, fp8 out; 64 nodes/block, no LDS ----------
// B-fragments read directly from L1-resident W1T (contiguous 16B/lane).
// 1563 blocks -> ~6 blocks/CU (occupancy fix); no staging, no syncthreads.
__global__ __launch_bounds__(256) void lin1_kernel(
    const float* __restrict__ emb, const float* __restrict__ deg,
    const float* __restrict__ seed, const short* __restrict__ w1t,
    const float* __restrict__ b1, unsigned char* __restrict__ out, int n) {
  const int t = threadIdx.x;
  const int base = blockIdx.x * 64;
  const int lane = t & 63, w = t >> 6;
  const int nl = lane & 15, q = lane >> 4;
  const short* pB = w1t + nl * W1TS + q * 8;
  const float bias0 = b1[nl], bias1 = b1[16 + nl],
              bias2 = b1[32 + nl], bias3 = b1[48 + nl];

  const int anode = base + w * 16 + nl;      // A-row this lane supplies
  bf16x8 afr[5];
  if (anode < n) {
    const float4* ep = (const float4*)(emb + (size_t)anode * IN_EMB);
#pragma unroll
    for (int kt = 0; kt < 4; ++kt) {
      float4 v0 = ep[q * 2 + kt * 8];
      float4 v1 = ep[q * 2 + 1 + kt * 8];
      bf16x8 a;
      a[0] = f2bfs(v0.x); a[1] = f2bfs(v0.y); a[2] = f2bfs(v0.z); a[3] = f2bfs(v0.w);
      a[4] = f2bfs(v1.x); a[5] = f2bfs(v1.y); a[6] = f2bfs(v1.z); a[7] = f2bfs(v1.w);
      afr[kt] = a;
    }
    bf16x8 a4 = {0, 0, 0, 0, 0, 0, 0, 0};
    if (q == 0) { a4[0] = f2bfs(deg[anode]); a4[1] = f2bfs(seed[anode]); }
    afr[4] = a4;
  } else {
#pragma unroll
    for (int kt = 0; kt < 5; ++kt) afr[kt] = (bf16x8){0, 0, 0, 0, 0, 0, 0, 0};
  }

  fx4 ac0 = {0.f, 0.f, 0.f, 0.f}, ac1 = ac0, ac2 = ac0, ac3 = ac0;
#pragma unroll
  for (int kt = 0; kt < 5; ++kt) {
    bf16x8 b0  = *(const bf16x8*)(pB + kt * 32);
    bf16x8 b1v = *(const bf16x8*)(pB + 16 * W1TS + kt * 32);
    bf16x8 b2v = *(const bf16x8*)(pB + 32 * W1TS + kt * 32);
    bf16x8 b3v = *(const bf16x8*)(pB + 48 * W1TS + kt * 32);
    ac0 = __builtin_amdgcn_mfma_f32_16x16x32_bf16(afr[kt], b0,  ac0, 0, 0, 0);
    ac1 = __builtin_amdgcn_mfma_f32_16x16x32_bf16(afr[kt], b1v, ac1, 0, 0, 0);
    ac2 = __builtin_amdgcn_mfma_f32_16x16x32_bf16(afr[kt], b2v, ac2, 0, 0, 0);
    ac3 = __builtin_amdgcn_mfma_f32_16x16x32_bf16(afr[kt], b3v, ac3, 0, 0, 0);
  }
#pragma unroll
  for (int r = 0; r < 4; ++r) {
    int node = base + w * 16 + q * 4 + r;
    if (node < n) {
      unsigned char* o = out + ((size_t)node << 6);
      o[nl]      = f2fp8(ac0[r] + bias0);
      o[16 + nl] = f2fp8(ac1[r] + bias1);
      o[32 + nl] = f2fp8(ac2[r] + bias2);
      o[48 + nl] = f2fp8(ac3[r] + bias3);
    }
  }
}

// ==== fp8 gather: one ROW per 8-lane subgroup (no cross-subgroup reduce) ====
#define GLD(ev, u)                                                            \
  const uint2 u = *(const uint2*)(xp + (((size_t)(unsigned)(ev)) << 6) + 8 * fl);
#define GMAD(ev, u)                                                           \
  {                                                                           \
    const float v = __int_as_float((int)((ev) >> 32));                        \
    const fx2 v2 = {v, v};                                                    \
    a0 += v2 * __builtin_amdgcn_cvt_pk_f32_fp8(u.x, false);                   \
    a1 += v2 * __builtin_amdgcn_cvt_pk_f32_fp8(u.x, true);                    \
    a2 += v2 * __builtin_amdgcn_cvt_pk_f32_fp8(u.y, false);                   \
    a3 += v2 * __builtin_amdgcn_cvt_pk_f32_fp8(u.y, true);                    \
  }
#define GMAD_P(ev, u, ok)                                                     \
  {                                                                           \
    const float v = (ok) ? __int_as_float((int)((ev) >> 32)) : 0.f;           \
    const fx2 v2 = {v, v};                                                    \
    a0 += v2 * __builtin_amdgcn_cvt_pk_f32_fp8(u.x, false);                   \
    a1 += v2 * __builtin_amdgcn_cvt_pk_f32_fp8(u.x, true);                    \
    a2 += v2 * __builtin_amdgcn_cvt_pk_f32_fp8(u.y, false);                   \
    a3 += v2 * __builtin_amdgcn_cvt_pk_f32_fp8(u.y, true);                    \
  }

#define SPMM_STAGE_EDGES                                                      \
  const unsigned long long* cep = (const unsigned long long*)ce;              \
  const int r0blk = blockIdx.x * RPB;                                         \
  const int bstartE = row_ptr[r0blk];                                         \
  const int bendE = row_ptr[(r0blk + RPB < n) ? (r0blk + RPB) : n];           \
  const int cnt = min(bendE - bstartE, ECAP);                                 \
  for (int ii = threadIdx.x; ii < cnt; ii += 256)                             \
    eb[ii] = __builtin_nontemporal_load(cep + bstartE + ii);                  \
  __syncthreads();

// per-subgroup gather of row r into a0..a3 (8 f32 in lane fl)
#define SPMM_GATHER_BODY                                                      \
  const int i0r = row_ptr[r];                                                 \
  const int endr = row_ptr[r + 1];                                            \
  const int lend = endr - bstartE;                                            \
  if (lend <= cnt) {                                                          \
    int i = i0r - bstartE;                                                    \
    for (; i + 4 <= lend; i += 4) {                                           \
      unsigned long long e0 = eb[i];                                          \
      unsigned long long e1 = eb[i + 1];                                      \
      unsigned long long e2 = eb[i + 2];                                      \
      unsigned long long e3 = eb[i + 3];                                      \
      GLD(e0, u0); GLD(e1, u1); GLD(e2, u2); GLD(e3, u3);                     \
      GMAD(e0, u0); GMAD(e1, u1); GMAD(e2, u2); GMAD(e3, u3);                 \
    }                                                                         \
    if (i < lend) {                                                           \
      const int last = lend - 1;                                              \
      bool k1 = i + 1 < lend, k2 = i + 2 < lend, k3 = i + 3 < lend;           \
      unsigned long long e0 = eb[i];                                          \
      unsigned long long e1 = eb[k1 ? i + 1 : last];                          \
      unsigned long long e2 = eb[k2 ? i + 2 : last];                          \
      unsigned long long e3 = eb[k3 ? i + 3 : last];                          \
      GLD(e0, u0); GLD(e1, u1); GLD(e2, u2); GLD(e3, u3);                     \
      GMAD(e0, u0); GMAD_P(e1, u1, k1);                                       \
      GMAD_P(e2, u2, k2); GMAD_P(e3, u3, k3);                                 \
    }                                                                         \
  } else {                                                                    \
    int i = i0r;                                                              \
    for (; i + 4 <= endr; i += 4) {                                           \
      unsigned long long e0 = __builtin_nontemporal_load(cep + i);            \
      unsigned long long e1 = __builtin_nontemporal_load(cep + i + 1);        \
      unsigned long long e2 = __builtin_nontemporal_load(cep + i + 2);        \
      unsigned long long e3 = __builtin_nontemporal_load(cep + i + 3);        \
      GLD(e0, u0); GLD(e1, u1); GLD(e2, u2); GLD(e3, u3);                     \
      GMAD(e0, u0); GMAD(e1, u1); GMAD(e2, u2); GMAD(e3, u3);                 \
    }                                                                         \
    if (i < endr) {                                                           \
      const int last = endr - 1;                                              \
      bool k1 = i + 1 < endr, k2 = i + 2 < endr, k3 = i + 3 < endr;           \
      unsigned long long e0 = cep[i];                                         \
      unsigned long long e1 = cep[k1 ? i + 1 : last];                         \
      unsigned long long e2 = cep[k2 ? i + 2 : last];                         \
      unsigned long long e3 = cep[k3 ? i + 3 : last];                         \
      GLD(e0, u0); GLD(e1, u1); GLD(e2, u2); GLD(e3, u3);                     \
      GMAD(e0, u0); GMAD_P(e1, u1, k1);                                       \
      GMAD_P(e2, u2, k2); GMAD_P(e3, u3, k3);                                 \
    }                                                                         \
  }

// ---------------- SpMM1 (exact CSR, fp8 gather) + fused ReLU -----------------
__global__ __launch_bounds__(256) void spmm_csr_kernel(
    const int* __restrict__ row_ptr, const int2* __restrict__ ce,
    const unsigned char* __restrict__ x, unsigned char* __restrict__ y, int n) {
  __shared__ unsigned long long eb[ECAP];
  const int fl = threadIdx.x & 7;
  const int r = blockIdx.x * RPB + (threadIdx.x >> 3);
  const unsigned char* xp = x;
  SPMM_STAGE_EDGES
  if (r < n) {
    fx2 a0 = {0.f, 0.f}, a1 = a0, a2 = a0, a3 = a0;
    SPMM_GATHER_BODY
    int lo = pk_fp8x4(fmaxf(a0.x, 0.f), fmaxf(a0.y, 0.f),
                      fmaxf(a1.x, 0.f), fmaxf(a1.y, 0.f));
    int hi = pk_fp8x4(fmaxf(a2.x, 0.f), fmaxf(a2.y, 0.f),
                      fmaxf(a3.x, 0.f), fmaxf(a3.y, 0.f));
    *(int2*)(y + ((size_t)r << 6) + 8 * fl) = make_int2(lo, hi);
  }
}

// ---------------- Linear2 via MFMA; 64 nodes/block, no LDS -------------------
__global__ __launch_bounds__(256) void lin2_kernel(
    const unsigned char* __restrict__ yin, const short* __restrict__ w2t,
    const float* __restrict__ b2, unsigned char* __restrict__ xout, int n) {
  const int t = threadIdx.x;
  const int base = blockIdx.x * 64;
  const int lane = t & 63, w = t >> 6;
  const int nl = lane & 15, q = lane >> 4;
  const short* pB = w2t + nl * 64 + q * 8;
  const float bias0 = b2[nl], bias1 = b2[16 + nl],
              bias2 = b2[32 + nl], bias3 = b2[48 + nl];

  const int anode = base + w * 16 + nl;
  const unsigned char* xg = yin + (((size_t)anode) << 6) + q * 8;
  fx4 ac0 = {0.f, 0.f, 0.f, 0.f}, ac1 = ac0, ac2 = ac0, ac3 = ac0;
#pragma unroll
  for (int kt = 0; kt < 2; ++kt) {
    uint2 u8 = (anode < n) ? *(const uint2*)(xg + kt * 32) : make_uint2(0u, 0u);
    fx2 f0 = __builtin_amdgcn_cvt_pk_f32_fp8(u8.x, false);
    fx2 f1 = __builtin_amdgcn_cvt_pk_f32_fp8(u8.x, true);
    fx2 f2 = __builtin_amdgcn_cvt_pk_f32_fp8(u8.y, false);
    fx2 f3 = __builtin_amdgcn_cvt_pk_f32_fp8(u8.y, true);
    bf16x8 a;
    a[0] = f2bfs(f0.x); a[1] = f2bfs(f0.y); a[2] = f2bfs(f1.x); a[3] = f2bfs(f1.y);
    a[4] = f2bfs(f2.x); a[5] = f2bfs(f2.y); a[6] = f2bfs(f3.x); a[7] = f2bfs(f3.y);
    bf16x8 b0  = *(const bf16x8*)(pB + kt * 32);
    bf16x8 b1v = *(const bf16x8*)(pB + 16 * 64 + kt * 32);
    bf16x8 b2v = *(const bf16x8*)(pB + 32 * 64 + kt * 32);
    bf16x8 b3v = *(const bf16x8*)(pB + 48 * 64 + kt * 32);
    ac0 = __builtin_amdgcn_mfma_f32_16x16x32_bf16(a, b0,  ac0, 0, 0, 0);
    ac1 = __builtin_amdgcn_mfma_f32_16x16x32_bf16(a, b1v, ac1, 0, 0, 0);
    ac2 = __builtin_amdgcn_mfma_f32_16x16x32_bf16(a, b2v, ac2, 0, 0, 0);
    ac3 = __builtin_amdgcn_mfma_f32_16x16x32_bf16(a, b3v, ac3, 0, 0, 0);
  }
#pragma unroll
  for (int r = 0; r < 4; ++r) {
    int node = base + w * 16 + q * 4 + r;
    if (node < n) {
      unsigned char* o = xout + ((size_t)node << 6);
      o[nl]      = f2fp8(ac0[r] + bias0);
      o[16 + nl] = f2fp8(ac1[r] + bias1);
      o[32 + nl] = f2fp8(ac2[r] + bias2);
      o[48 + nl] = f2fp8(ac3[r] + bias3);
    }
  }
}

// ---------------- SpMM2 (fp8 gather) + ReLU + Wout-dot -> block partial ------
__global__ __launch_bounds__(256) void spmm2_fused_kernel(
    const int* __restrict__ row_ptr, const int2* __restrict__ ce,
    const unsigned char* __restrict__ x, const float* __restrict__ Wout,
    float* __restrict__ partials, int n) {
  __shared__ unsigned long long eb[ECAP];
  const int fl = threadIdx.x & 7;
  const int r = blockIdx.x * RPB + (threadIdx.x >> 3);
  const unsigned char* xp = x;
  SPMM_STAGE_EDGES
  float wpart = 0.f;
  if (r < n) {
    fx2 a0 = {0.f, 0.f}, a1 = a0, a2 = a0, a3 = a0;
    SPMM_GATHER_BODY
    const float4 wv0 = ((const float4*)Wout)[2 * fl];
    const float4 wv1 = ((const float4*)Wout)[2 * fl + 1];
    wpart = fmaxf(a0.x, 0.f) * wv0.x + fmaxf(a0.y, 0.f) * wv0.y
          + fmaxf(a1.x, 0.f) * wv0.z + fmaxf(a1.y, 0.f) * wv0.w
          + fmaxf(a2.x, 0.f) * wv1.x + fmaxf(a2.y, 0.f) * wv1.y
          + fmaxf(a3.x, 0.f) * wv1.z + fmaxf(a3.y, 0.f) * wv1.w;
  }
  // full-wave reduce (sums all 8 subgroups' rows in this wave)
  for (int off = 32; off; off >>= 1) wpart += __shfl_down(wpart, off, 64);
  __shared__ float part[4];
  const int lane = threadIdx.x & 63;
  if (lane == 0) part[threadIdx.x >> 6] = wpart;
  __syncthreads();
  if (threadIdx.x == 0)
    partials[blockIdx.x] = part[0] + part[1] + part[2] + part[3];
}

// ---------------- final: sum partials (1 block, float4) ----------------------
__global__ __launch_bounds__(1024) void reduce_kernel(
    const float* __restrict__ partials, const float* __restrict__ bout,
    float* __restrict__ out, int m) {
  const int t = threadIdx.x;
  float s = 0.f;
  const int m4 = m >> 2;
  for (int i = t; i < m4; i += 1024) {
    float4 v = ((const float4*)partials)[i];
    s += v.x + v.y + v.z + v.w;
  }
  if (t < (m & 3)) s += partials[(m & ~3) + t];
  for (int off = 32; off; off >>= 1) s += __shfl_down(s, off, 64);
  __shared__ float wsum[16];
  if ((t & 63) == 0) wsum[t >> 6] = s;
  __syncthreads();
  if (t == 0) {
    float tot = bout[0];
    for (int w = 0; w < 16; ++w) tot += wsum[w];
    out[0] = tot;
  }
}

extern "C" void kernel_launch(void* const* d_in, const int* in_sizes, int n_in,
                              void* d_out, int out_size, void* d_ws, size_t ws_size,
                              hipStream_t stream) {
  const float* emb  = (const float*)d_in[0];
  const float* deg  = (const float*)d_in[1];
  const float* seed = (const float*)d_in[2];
  const int*   row  = (const int*)d_in[3];
  const int*   col  = (const int*)d_in[4];
  const float* vals = (const float*)d_in[5];
  const float* W1   = (const float*)d_in[6];
  const float* b1   = (const float*)d_in[7];
  const float* W2   = (const float*)d_in[8];
  const float* b2   = (const float*)d_in[9];
  const float* Wout = (const float*)d_in[10];
  const float* bout = (const float*)d_in[11];
  float* out = (float*)d_out;

  const int n  = in_sizes[0] / IN_EMB;   // 100000
  const int nE = in_sizes[3];            // 3200000
  const int nbkt = (n + ROWS_PER_BKT - 1) / ROWS_PER_BKT;   // 196

  const int lin_blocks  = (n + 63) / 64;        // 1563 (64 nodes/block)
  const int row_blocks  = (n + RPB - 1) / RPB;  // 3125 (32 rows/block)
  const int part_blocks = (nE + PART_CHUNK - 1) / PART_CHUNK;  // 782

  // ---- workspace layout ----
  char* ws = (char*)d_ws;
  int2* ce   = (int2*)ws;  ws += (size_t)nE * sizeof(int2);             // live to end
  char* tmpb = ws;
  int2* tmp  = (int2*)ws;  ws += (size_t)nbkt * SLOT_E * sizeof(int2);  // dead after sort
  unsigned char* xb = (unsigned char*)ws;  ws += ((size_t)n * HID + 255) & ~255ULL;  // fp8
  int* row_ptr = (int*)ws; ws += ((size_t)(n + 1) * 4 + 255) & ~255ULL;
  int* bcur    = (int*)ws; ws += ((size_t)nbkt * 4 + 255) & ~255ULL;
  int* bstart  = (int*)ws; ws += ((size_t)(nbkt + 1) * 4 + 255) & ~255ULL;
  short* w1t   = (short*)ws; ws += ((size_t)64 * W1TS * 2 + 255) & ~255ULL;
  short* w2t   = (short*)ws; ws += ((size_t)64 * 64 * 2 + 255) & ~255ULL;
  float* partials = (float*)ws;                                         // row_blocks floats
  // aliases into dead tmp region (28.9MB): xa at +0 (6.4MB), ya at +8MB
  // (6.4MB) -- disjoint; both used only after bucket_sort.
  unsigned char* xa = (unsigned char*)tmpb;
  unsigned char* ya = (unsigned char*)(tmpb + (8u << 20));

  // ---- weight prep + CSR build ----
  hipMemsetAsync(bcur, 0, (size_t)nbkt * sizeof(int), stream);
  wprep_kernel<<<2, 256, 0, stream>>>(W1, W2, w1t, w2t);
  partition_kernel<<<part_blocks, 512, 0, stream>>>(row, col, vals, bcur, tmp, nE);
  bscan_kernel<<<1, 1024, 0, stream>>>(bcur, bstart, row_ptr, n, nbkt);
  bucket_sort_kernel<<<nbkt, 512, 0, stream>>>(bstart, tmp, ce, row_ptr, n);

  // ---- network (full-width 64B activations, one pass per SpMM) ----
  lin1_kernel<<<lin_blocks, 256, 0, stream>>>(emb, deg, seed, w1t, b1, xa, n);
  spmm_csr_kernel<<<row_blocks, 256, 0, stream>>>(row_ptr, ce, xa, ya, n);
  lin2_kernel<<<lin_blocks, 256, 0, stream>>>(ya, w2t, b2, xb, n);
  spmm2_fused_kernel<<<row_blocks, 256, 0, stream>>>(row_ptr, ce, xb, Wout, partials, n);
  reduce_kernel<<<1, 1024, 0, stream>>>(partials, bout, out, row_blocks);
}

// Round 12
// 291.364 us; speedup vs baseline: 1.0039x; 1.0039x over previous
//
#include <hip/hip_runtime.h>
#include <hip/hip_bf16.h>

#define HID 64
#define IN_EMB 128
#define IN_DIM 130
#define ROWS_PER_BKT 512      // coarse buckets: 100000/512 -> 196 buckets
#define LOG_RPB 9
#define MAX_BKT 256           // >= nbkt (196); bcur allocated/zeroed to MAX_BKT
#define PART_CHUNK 4096       // edges per partition block (782 blocks)
#define SLOT_E 18432          // fixed tmp slot per bucket (mean 16384, sd 128 -> 16 sigma)
#define W1TS 160              // W1T row stride (k entries, zero-padded past 130)
#define SASTR 168             // lin1 sA row stride (shorts; 168*2B -> 2-way banks, free)
#define SYSTR 72              // lin2 sY row stride (bytes; 18 dwords -> conflict-free)
#define RPB 32                // rows per spmm block (one row per 8-lane subgroup)
#define ECAP 2048             // staged edges per spmm block (16KB LDS); avg 1024

typedef __hip_bfloat16 bf16;
typedef __attribute__((ext_vector_type(8))) short bf16x8;
typedef __attribute__((ext_vector_type(4))) float fx4;
typedef __attribute__((ext_vector_type(2))) float fx2;

__device__ __forceinline__ short f2bfs(float f) {
  __hip_bfloat16 h = __float2bfloat16(f);
  return *(reinterpret_cast<short*>(&h));
}
// pack 4 floats -> 4 fp8 e4m3 bytes (HW cvt)
__device__ __forceinline__ int pk_fp8x4(float a, float b, float c, float d) {
  int v = __builtin_amdgcn_cvt_pk_fp8_f32(a, b, 0, false);
  v = __builtin_amdgcn_cvt_pk_fp8_f32(c, d, v, true);
  return v;
}
__device__ __forceinline__ unsigned char f2fp8(float x) {
  return (unsigned char)(__builtin_amdgcn_cvt_pk_fp8_f32(x, x, 0, false) & 0xFF);
}

// ---------------- weight transpose prep + bcur zero --------------------------
// b0: W1T[c][k] 64 x W1TS bf16 (k zero-padded); b1: W2T[c][k] 64 x 64 bf16;
// b2: zero bcur[MAX_BKT]. Tables L1-resident downstream.
__global__ __launch_bounds__(256) void wprep_kernel(
    const float* __restrict__ W1, const float* __restrict__ W2,
    short* __restrict__ w1t, short* __restrict__ w2t, int* __restrict__ bcur) {
  const int t = threadIdx.x;
  if (blockIdx.x == 0) {
    for (int idx = t; idx < 64 * W1TS; idx += 256) {
      int c = idx / W1TS, k = idx % W1TS;
      w1t[idx] = f2bfs((k < IN_DIM) ? W1[k * HID + c] : 0.f);
    }
  } else if (blockIdx.x == 1) {
    for (int idx = t; idx < 64 * 64; idx += 256) {
      int c = idx >> 6, k = idx & 63;
      w2t[idx] = f2bfs(W2[k * HID + c]);
    }
  } else {
    if (t < MAX_BKT) bcur[t] = 0;
  }
}

// ---------------- partition: LDS-reordered scatter (coalesced stores) --------
__global__ __launch_bounds__(512) void partition_kernel(
    const int* __restrict__ row, const int* __restrict__ col,
    const float* __restrict__ vals, int* __restrict__ bcur,
    int2* __restrict__ tmp, int nE) {
  __shared__ int2 lbuf[PART_CHUNK];            // 32 KB
  __shared__ unsigned char lbid[PART_CHUNK];   // 4 KB: bucket id per slot
  __shared__ int h[MAX_BKT];
  __shared__ int sc[MAX_BKT];
  __shared__ int lofs[MAX_BKT + 1];
  __shared__ int lcur[MAX_BKT];
  __shared__ int gbase[MAX_BKT];
  const int t = threadIdx.x;
  const int base = blockIdx.x * PART_CHUNK;    // multiple of 4096
  const int cntE = min(PART_CHUNK, nE - base);

  if (t < MAX_BKT) h[t] = 0;
  __syncthreads();
  // phase 1: histogram
  for (int kk = t; kk < PART_CHUNK / 4; kk += 512) {
    int e0 = base + kk * 4;
    if (e0 + 3 < nE) {
      int4 r4 = ((const int4*)row)[(base >> 2) + kk];
      atomicAdd(&h[r4.x >> LOG_RPB], 1);
      atomicAdd(&h[r4.y >> LOG_RPB], 1);
      atomicAdd(&h[r4.z >> LOG_RPB], 1);
      atomicAdd(&h[r4.w >> LOG_RPB], 1);
    } else {
      for (int j = 0; j < 4; ++j) {
        int e = e0 + j;
        if (e < nE) atomicAdd(&h[row[e] >> LOG_RPB], 1);
      }
    }
  }
  __syncthreads();
  // phase 2: exclusive prefix + global reservation
  if (t < MAX_BKT) sc[t] = h[t];
  __syncthreads();
  for (int off = 1; off < MAX_BKT; off <<= 1) {
    int u = (t < MAX_BKT && t >= off) ? sc[t - off] : 0;
    __syncthreads();
    if (t < MAX_BKT) sc[t] += u;
    __syncthreads();
  }
  if (t < MAX_BKT) {
    int ex = sc[t] - h[t];
    lofs[t] = ex;
    lcur[t] = ex;
    if (h[t] > 0) gbase[t] = t * SLOT_E + atomicAdd(&bcur[t], h[t]);
  }
  if (t == MAX_BKT - 1) lofs[MAX_BKT] = sc[t];   // == cntE
  __syncthreads();
  // phase 3: scatter into bucket-major LDS buffer
  for (int kk = t; kk < PART_CHUNK / 4; kk += 512) {
    int e0 = base + kk * 4;
    if (e0 + 3 < nE) {
      int4 r4 = ((const int4*)row)[(base >> 2) + kk];
      int4 c4 = ((const int4*)col)[(base >> 2) + kk];
      float4 v4 = ((const float4*)vals)[(base >> 2) + kk];
      int rr[4] = {r4.x, r4.y, r4.z, r4.w};
      int cc[4] = {c4.x, c4.y, c4.z, c4.w};
      float vv[4] = {v4.x, v4.y, v4.z, v4.w};
#pragma unroll
      for (int j = 0; j < 4; ++j) {
        int b = rr[j] >> LOG_RPB;
        int p = atomicAdd(&lcur[b], 1);
        lbuf[p] = make_int2(cc[j] | ((rr[j] & (ROWS_PER_BKT - 1)) << 20),
                            __float_as_int(vv[j]));
        lbid[p] = (unsigned char)b;
      }
    } else {
      for (int j = 0; j < 4; ++j) {
        int e = e0 + j;
        if (e < nE) {
          int r = row[e];
          int b = r >> LOG_RPB;
          int p = atomicAdd(&lcur[b], 1);
          lbuf[p] = make_int2(col[e] | ((r & (ROWS_PER_BKT - 1)) << 20),
                              __float_as_int(vals[e]));
          lbid[p] = (unsigned char)b;
        }
      }
    }
  }
  __syncthreads();
  // phase 4: coalesced copy-out
  for (int i = t; i < cntE; i += 512) {
    int b = lbid[i];
    int off = i - lofs[b];
    int g = gbase[b] + off;
    if (g - b * SLOT_E < SLOT_E) tmp[g] = lbuf[i];
  }
}

// ---------------- per-bucket counting sort (scan fused; no bscan kernel) -----
// Each block reads the 256 final bucket counts (bcur after partition), scans
// them in LDS (one-time, trivial), derives its own bstart. Block nbkt-1 also
// writes row_ptr[n] = nE.
__global__ __launch_bounds__(512) void bucket_sort_kernel(
    const int* __restrict__ bcurf, const int2* __restrict__ tmp,
    int2* __restrict__ ce, int* __restrict__ row_ptr, int n) {
  __shared__ int binc[MAX_BKT];
  __shared__ int bcnt_s[MAX_BKT];
  __shared__ int rcnt[ROWS_PER_BKT];
  __shared__ int rpos[ROWS_PER_BKT];
  __shared__ int sc[ROWS_PER_BKT];
  const int t = threadIdx.x;
  const int b = blockIdx.x;
  if (t < MAX_BKT) { int c = bcurf[t]; bcnt_s[t] = c; binc[t] = c; }
  __syncthreads();
  for (int off = 1; off < MAX_BKT; off <<= 1) {
    int u = (t < MAX_BKT && t >= off) ? binc[t - off] : 0;
    __syncthreads();
    if (t < MAX_BKT) binc[t] += u;
    __syncthreads();
  }
  const int start = binc[b] - bcnt_s[b];
  const int len   = bcnt_s[b];
  if (b == gridDim.x - 1 && t == 0) row_ptr[n] = binc[MAX_BKT - 1];   // == nE
  const int2* ts = tmp + (size_t)b * SLOT_E;
  rcnt[t] = 0;
  __syncthreads();
  const int* keys = (const int*)ts;              // ts[i].x at index 2*i
  for (int i = t; i < len; i += 512)
    atomicAdd(&rcnt[((unsigned)keys[2 * i]) >> 20], 1);
  __syncthreads();
  sc[t] = rcnt[t];
  __syncthreads();
  for (int off = 1; off < ROWS_PER_BKT; off <<= 1) {
    int u = (t >= off) ? sc[t - off] : 0;
    __syncthreads();
    sc[t] += u;
    __syncthreads();
  }
  {
    int ex = sc[t] - rcnt[t];
    int gpos = start + ex;
    rpos[t] = gpos;
    int gr = b * ROWS_PER_BKT + t;
    if (gr < n) row_ptr[gr] = gpos;
  }
  __syncthreads();
  for (int i = t; i < len; i += 512) {
    int2 e = ts[i];
    int p = atomicAdd(&rpos[((unsigned)e.x) >> 20], 1);
    ce[p] = make_int2(e.x & 0xFFFFF, e.y);
  }
}

// ---------------- Linear1: coalesced sA staging + global-L1 W1T --------------
// 64 nodes/block (1563 blocks ~6/CU). emb staged coalesced into bf16 LDS
// (21.5KB, 2-way-free banks); B-fragments straight from L1-resident w1t.
__global__ __launch_bounds__(256) void lin1_kernel(
    const float* __restrict__ emb, const float* __restrict__ deg,
    const float* __restrict__ seed, const short* __restrict__ w1t,
    const float* __restrict__ b1, unsigned char* __restrict__ out, int n) {
  __shared__ short sA[64 * SASTR];
  const int t = threadIdx.x;
  const int base = blockIdx.x * 64;

  // stage emb rows, fully coalesced (thread t -> 16B chunk t%32 of node t/32 ...)
  for (int idx = t; idx < 64 * 32; idx += 256) {
    int nn = idx >> 5, k4 = idx & 31;
    int node = base + nn;
    short4 wv;
    if (node < n) {
      float4 v = ((const float4*)emb)[(size_t)node * 32 + k4];
      wv = make_short4(f2bfs(v.x), f2bfs(v.y), f2bfs(v.z), f2bfs(v.w));
    } else {
      wv = make_short4(0, 0, 0, 0);
    }
    *(short4*)&sA[nn * SASTR + 4 * k4] = wv;
  }
  // deg/seed + zero pad (k = 128..159)
  for (int idx = t; idx < 64 * 32; idx += 256) {
    int nn = idx >> 5, kk = idx & 31;
    int node = base + nn;
    float v = 0.f;
    if (node < n) {
      if (kk == 0) v = deg[node];
      else if (kk == 1) v = seed[node];
    }
    sA[nn * SASTR + 128 + kk] = f2bfs(v);
  }
  __syncthreads();

  const int lane = t & 63, w = t >> 6;
  const int nl = lane & 15, q = lane >> 4;
  const short* pA = &sA[(w * 16 + nl) * SASTR + q * 8];
  const short* pB = w1t + nl * W1TS + q * 8;
  const float bias0 = b1[nl], bias1 = b1[16 + nl],
              bias2 = b1[32 + nl], bias3 = b1[48 + nl];

  fx4 ac0 = {0.f, 0.f, 0.f, 0.f}, ac1 = ac0, ac2 = ac0, ac3 = ac0;
#pragma unroll
  for (int kt = 0; kt < 5; ++kt) {
    bf16x8 a   = *(const bf16x8*)(pA + kt * 32);
    bf16x8 b0  = *(const bf16x8*)(pB + kt * 32);
    bf16x8 b1v = *(const bf16x8*)(pB + 16 * W1TS + kt * 32);
    bf16x8 b2v = *(const bf16x8*)(pB + 32 * W1TS + kt * 32);
    bf16x8 b3v = *(const bf16x8*)(pB + 48 * W1TS + kt * 32);
    ac0 = __builtin_amdgcn_mfma_f32_16x16x32_bf16(a, b0,  ac0, 0, 0, 0);
    ac1 = __builtin_amdgcn_mfma_f32_16x16x32_bf16(a, b1v, ac1, 0, 0, 0);
    ac2 = __builtin_amdgcn_mfma_f32_16x16x32_bf16(a, b2v, ac2, 0, 0, 0);
    ac3 = __builtin_amdgcn_mfma_f32_16x16x32_bf16(a, b3v, ac3, 0, 0, 0);
  }
#pragma unroll
  for (int r = 0; r < 4; ++r) {
    int node = base + w * 16 + q * 4 + r;
    if (node < n) {
      unsigned char* o = out + ((size_t)node << 6);
      o[nl]      = f2fp8(ac0[r] + bias0);
      o[16 + nl] = f2fp8(ac1[r] + bias1);
      o[32 + nl] = f2fp8(ac2[r] + bias2);
      o[48 + nl] = f2fp8(ac3[r] + bias3);
    }
  }
}

// ==== fp8 gather: one ROW per 8-lane subgroup (no cross-subgroup reduce) ====
#define GLD(ev, u)                                                            \
  const uint2 u = *(const uint2*)(xp + (((size_t)(unsigned)(ev)) << 6) + 8 * fl);
#define GMAD(ev, u)                                                           \
  {                                                                           \
    const float v = __int_as_float((int)((ev) >> 32));                        \
    const fx2 v2 = {v, v};                                                    \
    a0 += v2 * __builtin_amdgcn_cvt_pk_f32_fp8(u.x, false);                   \
    a1 += v2 * __builtin_amdgcn_cvt_pk_f32_fp8(u.x, true);                    \
    a2 += v2 * __builtin_amdgcn_cvt_pk_f32_fp8(u.y, false);                   \
    a3 += v2 * __builtin_amdgcn_cvt_pk_f32_fp8(u.y, true);                    \
  }
#define GMAD_P(ev, u, ok)                                                     \
  {                                                                           \
    const float v = (ok) ? __int_as_float((int)((ev) >> 32)) : 0.f;           \
    const fx2 v2 = {v, v};                                                    \
    a0 += v2 * __builtin_amdgcn_cvt_pk_f32_fp8(u.x, false);                   \
    a1 += v2 * __builtin_amdgcn_cvt_pk_f32_fp8(u.x, true);                    \
    a2 += v2 * __builtin_amdgcn_cvt_pk_f32_fp8(u.y, false);                   \
    a3 += v2 * __builtin_amdgcn_cvt_pk_f32_fp8(u.y, true);                    \
  }

#define SPMM_STAGE_EDGES                                                      \
  const unsigned long long* cep = (const unsigned long long*)ce;              \
  const int r0blk = blockIdx.x * RPB;                                         \
  const int bstartE = row_ptr[r0blk];                                         \
  const int bendE = row_ptr[(r0blk + RPB < n) ? (r0blk + RPB) : n];           \
  const int cnt = min(bendE - bstartE, ECAP);                                 \
  for (int ii = threadIdx.x; ii < cnt; ii += 256)                             \
    eb[ii] = __builtin_nontemporal_load(cep + bstartE + ii);                  \
  __syncthreads();

// per-subgroup gather of row r into a0..a3 (8 f32 in lane fl)
#define SPMM_GATHER_BODY                                                      \
  const int i0r = row_ptr[r];                                                 \
  const int endr = row_ptr[r + 1];                                            \
  const int lend = endr - bstartE;                                            \
  if (lend <= cnt) {                                                          \
    int i = i0r - bstartE;                                                    \
    for (; i + 4 <= lend; i += 4) {                                           \
      unsigned long long e0 = eb[i];                                          \
      unsigned long long e1 = eb[i + 1];                                      \
      unsigned long long e2 = eb[i + 2];                                      \
      unsigned long long e3 = eb[i + 3];                                      \
      GLD(e0, u0); GLD(e1, u1); GLD(e2, u2); GLD(e3, u3);                     \
      GMAD(e0, u0); GMAD(e1, u1); GMAD(e2, u2); GMAD(e3, u3);                 \
    }                                                                         \
    if (i < lend) {                                                           \
      const int last = lend - 1;                                              \
      bool k1 = i + 1 < lend, k2 = i + 2 < lend, k3 = i + 3 < lend;           \
      unsigned long long e0 = eb[i];                                          \
      unsigned long long e1 = eb[k1 ? i + 1 : last];                          \
      unsigned long long e2 = eb[k2 ? i + 2 : last];                          \
      unsigned long long e3 = eb[k3 ? i + 3 : last];                          \
      GLD(e0, u0); GLD(e1, u1); GLD(e2, u2); GLD(e3, u3);                     \
      GMAD(e0, u0); GMAD_P(e1, u1, k1);                                       \
      GMAD_P(e2, u2, k2); GMAD_P(e3, u3, k3);                                 \
    }                                                                         \
  } else {                                                                    \
    int i = i0r;                                                              \
    for (; i + 4 <= endr; i += 4) {                                           \
      unsigned long long e0 = __builtin_nontemporal_load(cep + i);            \
      unsigned long long e1 = __builtin_nontemporal_load(cep + i + 1);        \
      unsigned long long e2 = __builtin_nontemporal_load(cep + i + 2);        \
      unsigned long long e3 = __builtin_nontemporal_load(cep + i + 3);        \
      GLD(e0, u0); GLD(e1, u1); GLD(e2, u2); GLD(e3, u3);                     \
      GMAD(e0, u0); GMAD(e1, u1); GMAD(e2, u2); GMAD(e3, u3);                 \
    }                                                                         \
    if (i < endr) {                                                           \
      const int last = endr - 1;                                              \
      bool k1 = i + 1 < endr, k2 = i + 2 < endr, k3 = i + 3 < endr;           \
      unsigned long long e0 = cep[i];                                         \
      unsigned long long e1 = cep[k1 ? i + 1 : last];                         \
      unsigned long long e2 = cep[k2 ? i + 2 : last];                         \
      unsigned long long e3 = cep[k3 ? i + 3 : last];                         \
      GLD(e0, u0); GLD(e1, u1); GLD(e2, u2); GLD(e3, u3);                     \
      GMAD(e0, u0); GMAD_P(e1, u1, k1);                                       \
      GMAD_P(e2, u2, k2); GMAD_P(e3, u3, k3);                                 \
    }                                                                         \
  }

// ---------------- SpMM1 (exact CSR, fp8 gather) + fused ReLU -----------------
__global__ __launch_bounds__(256) void spmm_csr_kernel(
    const int* __restrict__ row_ptr, const int2* __restrict__ ce,
    const unsigned char* __restrict__ x, unsigned char* __restrict__ y, int n) {
  __shared__ unsigned long long eb[ECAP];
  const int fl = threadIdx.x & 7;
  const int r = blockIdx.x * RPB + (threadIdx.x >> 3);
  const unsigned char* xp = x;
  SPMM_STAGE_EDGES
  if (r < n) {
    fx2 a0 = {0.f, 0.f}, a1 = a0, a2 = a0, a3 = a0;
    SPMM_GATHER_BODY
    int lo = pk_fp8x4(fmaxf(a0.x, 0.f), fmaxf(a0.y, 0.f),
                      fmaxf(a1.x, 0.f), fmaxf(a1.y, 0.f));
    int hi = pk_fp8x4(fmaxf(a2.x, 0.f), fmaxf(a2.y, 0.f),
                      fmaxf(a3.x, 0.f), fmaxf(a3.y, 0.f));
    *(int2*)(y + ((size_t)r << 6) + 8 * fl) = make_int2(lo, hi);
  }
}

// ---------------- Linear2: coalesced sY staging + global-L1 W2T --------------
// 64 nodes/block; y staged into 4.6KB LDS (72B rows, conflict-free b64 reads).
__global__ __launch_bounds__(256) void lin2_kernel(
    const unsigned char* __restrict__ yin, const short* __restrict__ w2t,
    const float* __restrict__ b2, unsigned char* __restrict__ xout, int n) {
  __shared__ unsigned char sY[64 * SYSTR];
  const int t = threadIdx.x;
  const int base = blockIdx.x * 64;
  {
    int nn = t >> 2, c4 = t & 3;
    int node = base + nn;
    uint4 v = make_uint4(0u, 0u, 0u, 0u);
    if (node < n) v = ((const uint4*)yin)[(size_t)node * 4 + c4];
    *(uint4*)&sY[nn * SYSTR + 16 * c4] = v;
  }
  __syncthreads();

  const int lane = t & 63, w = t >> 6;
  const int nl = lane & 15, q = lane >> 4;
  const unsigned char* pY = &sY[(w * 16 + nl) * SYSTR + q * 8];
  const short* pB = w2t + nl * 64 + q * 8;
  const float bias0 = b2[nl], bias1 = b2[16 + nl],
              bias2 = b2[32 + nl], bias3 = b2[48 + nl];

  fx4 ac0 = {0.f, 0.f, 0.f, 0.f}, ac1 = ac0, ac2 = ac0, ac3 = ac0;
#pragma unroll
  for (int kt = 0; kt < 2; ++kt) {
    uint2 u8 = *(const uint2*)(pY + kt * 32);
    fx2 f0 = __builtin_amdgcn_cvt_pk_f32_fp8(u8.x, false);
    fx2 f1 = __builtin_amdgcn_cvt_pk_f32_fp8(u8.x, true);
    fx2 f2 = __builtin_amdgcn_cvt_pk_f32_fp8(u8.y, false);
    fx2 f3 = __builtin_amdgcn_cvt_pk_f32_fp8(u8.y, true);
    bf16x8 a;
    a[0] = f2bfs(f0.x); a[1] = f2bfs(f0.y); a[2] = f2bfs(f1.x); a[3] = f2bfs(f1.y);
    a[4] = f2bfs(f2.x); a[5] = f2bfs(f2.y); a[6] = f2bfs(f3.x); a[7] = f2bfs(f3.y);
    bf16x8 b0  = *(const bf16x8*)(pB + kt * 32);
    bf16x8 b1v = *(const bf16x8*)(pB + 16 * 64 + kt * 32);
    bf16x8 b2v = *(const bf16x8*)(pB + 32 * 64 + kt * 32);
    bf16x8 b3v = *(const bf16x8*)(pB + 48 * 64 + kt * 32);
    ac0 = __builtin_amdgcn_mfma_f32_16x16x32_bf16(a, b0,  ac0, 0, 0, 0);
    ac1 = __builtin_amdgcn_mfma_f32_16x16x32_bf16(a, b1v, ac1, 0, 0, 0);
    ac2 = __builtin_amdgcn_mfma_f32_16x16x32_bf16(a, b2v, ac2, 0, 0, 0);
    ac3 = __builtin_amdgcn_mfma_f32_16x16x32_bf16(a, b3v, ac3, 0, 0, 0);
  }
#pragma unroll
  for (int r = 0; r < 4; ++r) {
    int node = base + w * 16 + q * 4 + r;
    if (node < n) {
      unsigned char* o = xout + ((size_t)node << 6);
      o[nl]      = f2fp8(ac0[r] + bias0);
      o[16 + nl] = f2fp8(ac1[r] + bias1);
      o[32 + nl] = f2fp8(ac2[r] + bias2);
      o[48 + nl] = f2fp8(ac3[r] + bias3);
    }
  }
}

// ---------------- SpMM2 (fp8 gather) + ReLU + Wout-dot -> block partial ------
__global__ __launch_bounds__(256) void spmm2_fused_kernel(
    const int* __restrict__ row_ptr, const int2* __restrict__ ce,
    const unsigned char* __restrict__ x, const float* __restrict__ Wout,
    float* __restrict__ partials, int n) {
  __shared__ unsigned long long eb[ECAP];
  const int fl = threadIdx.x & 7;
  const int r = blockIdx.x * RPB + (threadIdx.x >> 3);
  const unsigned char* xp = x;
  SPMM_STAGE_EDGES
  float wpart = 0.f;
  if (r < n) {
    fx2 a0 = {0.f, 0.f}, a1 = a0, a2 = a0, a3 = a0;
    SPMM_GATHER_BODY
    const float4 wv0 = ((const float4*)Wout)[2 * fl];
    const float4 wv1 = ((const float4*)Wout)[2 * fl + 1];
    wpart = fmaxf(a0.x, 0.f) * wv0.x + fmaxf(a0.y, 0.f) * wv0.y
          + fmaxf(a1.x, 0.f) * wv0.z + fmaxf(a1.y, 0.f) * wv0.w
          + fmaxf(a2.x, 0.f) * wv1.x + fmaxf(a2.y, 0.f) * wv1.y
          + fmaxf(a3.x, 0.f) * wv1.z + fmaxf(a3.y, 0.f) * wv1.w;
  }
  // full-wave reduce (sums all 8 subgroups' rows in this wave)
  for (int off = 32; off; off >>= 1) wpart += __shfl_down(wpart, off, 64);
  __shared__ float part[4];
  const int lane = threadIdx.x & 63;
  if (lane == 0) part[threadIdx.x >> 6] = wpart;
  __syncthreads();
  if (threadIdx.x == 0)
    partials[blockIdx.x] = part[0] + part[1] + part[2] + part[3];
}

// ---------------- final: sum partials (1 block, float4) ----------------------
__global__ __launch_bounds__(1024) void reduce_kernel(
    const float* __restrict__ partials, const float* __restrict__ bout,
    float* __restrict__ out, int m) {
  const int t = threadIdx.x;
  float s = 0.f;
  const int m4 = m >> 2;
  for (int i = t; i < m4; i += 1024) {
    float4 v = ((const float4*)partials)[i];
    s += v.x + v.y + v.z + v.w;
  }
  if (t < (m & 3)) s += partials[(m & ~3) + t];
  for (int off = 32; off; off >>= 1) s += __shfl_down(s, off, 64);
  __shared__ float wsum[16];
  if ((t & 63) == 0) wsum[t >> 6] = s;
  __syncthreads();
  if (t == 0) {
    float tot = bout[0];
    for (int w = 0; w < 16; ++w) tot += wsum[w];
    out[0] = tot;
  }
}

extern "C" void kernel_launch(void* const* d_in, const int* in_sizes, int n_in,
                              void* d_out, int out_size, void* d_ws, size_t ws_size,
                              hipStream_t stream) {
  const float* emb  = (const float*)d_in[0];
  const float* deg  = (const float*)d_in[1];
  const float* seed = (const float*)d_in[2];
  const int*   row  = (const int*)d_in[3];
  const int*   col  = (const int*)d_in[4];
  const float* vals = (const float*)d_in[5];
  const float* W1   = (const float*)d_in[6];
  const float* b1   = (const float*)d_in[7];
  const float* W2   = (const float*)d_in[8];
  const float* b2   = (const float*)d_in[9];
  const float* Wout = (const float*)d_in[10];
  const float* bout = (const float*)d_in[11];
  float* out = (float*)d_out;

  const int n  = in_sizes[0] / IN_EMB;   // 100000
  const int nE = in_sizes[3];            // 3200000
  const int nbkt = (n + ROWS_PER_BKT - 1) / ROWS_PER_BKT;   // 196

  const int lin_blocks  = (n + 63) / 64;        // 1563 (64 nodes/block)
  const int row_blocks  = (n + RPB - 1) / RPB;  // 3125 (32 rows/block)
  const int part_blocks = (nE + PART_CHUNK - 1) / PART_CHUNK;  // 782

  // ---- workspace layout ----
  char* ws = (char*)d_ws;
  int2* ce   = (int2*)ws;  ws += (size_t)nE * sizeof(int2);             // live to end
  char* tmpb = ws;
  int2* tmp  = (int2*)ws;  ws += (size_t)nbkt * SLOT_E * sizeof(int2);  // dead after sort
  unsigned char* xb = (unsigned char*)ws;  ws += ((size_t)n * HID + 255) & ~255ULL;  // fp8
  int* row_ptr = (int*)ws; ws += ((size_t)(n + 1) * 4 + 255) & ~255ULL;
  int* bcur    = (int*)ws; ws += ((size_t)MAX_BKT * 4 + 255) & ~255ULL;
  short* w1t   = (short*)ws; ws += ((size_t)64 * W1TS * 2 + 255) & ~255ULL;
  short* w2t   = (short*)ws; ws += ((size_t)64 * 64 * 2 + 255) & ~255ULL;
  float* partials = (float*)ws;                                         // row_blocks floats
  // aliases into dead tmp region (28.9MB): xa at +0 (6.4MB), ya at +8MB
  // (6.4MB) -- disjoint; both used only after bucket_sort.
  unsigned char* xa = (unsigned char*)tmpb;
  unsigned char* ya = (unsigned char*)(tmpb + (8u << 20));

  // ---- weight prep (also zeroes bcur) + CSR build (bscan fused into sort) ----
  wprep_kernel<<<3, 256, 0, stream>>>(W1, W2, w1t, w2t, bcur);
  partition_kernel<<<part_blocks, 512, 0, stream>>>(row, col, vals, bcur, tmp, nE);
  bucket_sort_kernel<<<nbkt, 512, 0, stream>>>(bcur, tmp, ce, row_ptr, n);

  // ---- network (full-width 64B activations, one pass per SpMM) ----
  lin1_kernel<<<lin_blocks, 256, 0, stream>>>(emb, deg, seed, w1t, b1, xa, n);
  spmm_csr_kernel<<<row_blocks, 256, 0, stream>>>(row_ptr, ce, xa, ya, n);
  lin2_kernel<<<lin_blocks, 256, 0, stream>>>(ya, w2t, b2, xb, n);
  spmm2_fused_kernel<<<row_blocks, 256, 0, stream>>>(row_ptr, ce, xb, Wout, partials, n);
  reduce_kernel<<<1, 1024, 0, stream>>>(partials, bout, out, row_blocks);
}

// Round 13
// 286.339 us; speedup vs baseline: 1.0215x; 1.0175x over previous
//
#include <hip/hip_runtime.h>
#include <hip/hip_bf16.h>

#define HID 64
#define IN_EMB 128
#define IN_DIM 130
#define ROWS_PER_BKT 512      // coarse buckets: 100000/512 -> 196 buckets
#define LOG_RPB 9
#define MAX_BKT 256           // >= nbkt (196); bcur allocated/zeroed to MAX_BKT
#define PART_CHUNK 4096       // edges per partition block (782 blocks)
#define SLOT_E 18432          // fixed tmp slot per bucket (mean 16384, sd 128 -> 16 sigma)
#define W1TS 160              // W1T row stride (k entries, zero-padded past 130)
#define SASTR 168             // lin1 sA row stride (shorts; 2-way banks, free)
#define SYSTR 72              // fused-lin2 sY row stride (bytes)
#define RPB 32                // rows per spmm block (one row per 8-lane subgroup)
#define ECAP 2048             // staged edges per spmm block (16KB LDS); avg 1024

typedef __hip_bfloat16 bf16;
typedef __attribute__((ext_vector_type(8))) short bf16x8;
typedef __attribute__((ext_vector_type(4))) float fx4;
typedef __attribute__((ext_vector_type(2))) float fx2;

__device__ __forceinline__ short f2bfs(float f) {
  __hip_bfloat16 h = __float2bfloat16(f);
  return *(reinterpret_cast<short*>(&h));
}
// pack 4 floats -> 4 fp8 e4m3 bytes (HW cvt)
__device__ __forceinline__ int pk_fp8x4(float a, float b, float c, float d) {
  int v = __builtin_amdgcn_cvt_pk_fp8_f32(a, b, 0, false);
  v = __builtin_amdgcn_cvt_pk_fp8_f32(c, d, v, true);
  return v;
}
__device__ __forceinline__ unsigned char f2fp8(float x) {
  return (unsigned char)(__builtin_amdgcn_cvt_pk_fp8_f32(x, x, 0, false) & 0xFF);
}

// ---------------- weight transpose prep + bcur zero --------------------------
__global__ __launch_bounds__(256) void wprep_kernel(
    const float* __restrict__ W1, const float* __restrict__ W2,
    short* __restrict__ w1t, short* __restrict__ w2t, int* __restrict__ bcur) {
  const int t = threadIdx.x;
  if (blockIdx.x == 0) {
    for (int idx = t; idx < 64 * W1TS; idx += 256) {
      int c = idx / W1TS, k = idx % W1TS;
      w1t[idx] = f2bfs((k < IN_DIM) ? W1[k * HID + c] : 0.f);
    }
  } else if (blockIdx.x == 1) {
    for (int idx = t; idx < 64 * 64; idx += 256) {
      int c = idx >> 6, k = idx & 63;
      w2t[idx] = f2bfs(W2[k * HID + c]);
    }
  } else {
    if (t < MAX_BKT) bcur[t] = 0;
  }
}

// ---------------- partition: LDS-reordered scatter (coalesced stores) --------
__global__ __launch_bounds__(512) void partition_kernel(
    const int* __restrict__ row, const int* __restrict__ col,
    const float* __restrict__ vals, int* __restrict__ bcur,
    int2* __restrict__ tmp, int nE) {
  __shared__ int2 lbuf[PART_CHUNK];            // 32 KB
  __shared__ unsigned char lbid[PART_CHUNK];   // 4 KB: bucket id per slot
  __shared__ int h[MAX_BKT];
  __shared__ int sc[MAX_BKT];
  __shared__ int lofs[MAX_BKT + 1];
  __shared__ int lcur[MAX_BKT];
  __shared__ int gbase[MAX_BKT];
  const int t = threadIdx.x;
  const int base = blockIdx.x * PART_CHUNK;    // multiple of 4096
  const int cntE = min(PART_CHUNK, nE - base);

  if (t < MAX_BKT) h[t] = 0;
  __syncthreads();
  // phase 1: histogram
  for (int kk = t; kk < PART_CHUNK / 4; kk += 512) {
    int e0 = base + kk * 4;
    if (e0 + 3 < nE) {
      int4 r4 = ((const int4*)row)[(base >> 2) + kk];
      atomicAdd(&h[r4.x >> LOG_RPB], 1);
      atomicAdd(&h[r4.y >> LOG_RPB], 1);
      atomicAdd(&h[r4.z >> LOG_RPB], 1);
      atomicAdd(&h[r4.w >> LOG_RPB], 1);
    } else {
      for (int j = 0; j < 4; ++j) {
        int e = e0 + j;
        if (e < nE) atomicAdd(&h[row[e] >> LOG_RPB], 1);
      }
    }
  }
  __syncthreads();
  // phase 2: exclusive prefix + global reservation
  if (t < MAX_BKT) sc[t] = h[t];
  __syncthreads();
  for (int off = 1; off < MAX_BKT; off <<= 1) {
    int u = (t < MAX_BKT && t >= off) ? sc[t - off] : 0;
    __syncthreads();
    if (t < MAX_BKT) sc[t] += u;
    __syncthreads();
  }
  if (t < MAX_BKT) {
    int ex = sc[t] - h[t];
    lofs[t] = ex;
    lcur[t] = ex;
    if (h[t] > 0) gbase[t] = t * SLOT_E + atomicAdd(&bcur[t], h[t]);
  }
  if (t == MAX_BKT - 1) lofs[MAX_BKT] = sc[t];   // == cntE
  __syncthreads();
  // phase 3: scatter into bucket-major LDS buffer
  for (int kk = t; kk < PART_CHUNK / 4; kk += 512) {
    int e0 = base + kk * 4;
    if (e0 + 3 < nE) {
      int4 r4 = ((const int4*)row)[(base >> 2) + kk];
      int4 c4 = ((const int4*)col)[(base >> 2) + kk];
      float4 v4 = ((const float4*)vals)[(base >> 2) + kk];
      int rr[4] = {r4.x, r4.y, r4.z, r4.w};
      int cc[4] = {c4.x, c4.y, c4.z, c4.w};
      float vv[4] = {v4.x, v4.y, v4.z, v4.w};
#pragma unroll
      for (int j = 0; j < 4; ++j) {
        int b = rr[j] >> LOG_RPB;
        int p = atomicAdd(&lcur[b], 1);
        lbuf[p] = make_int2(cc[j] | ((rr[j] & (ROWS_PER_BKT - 1)) << 20),
                            __float_as_int(vv[j]));
        lbid[p] = (unsigned char)b;
      }
    } else {
      for (int j = 0; j < 4; ++j) {
        int e = e0 + j;
        if (e < nE) {
          int r = row[e];
          int b = r >> LOG_RPB;
          int p = atomicAdd(&lcur[b], 1);
          lbuf[p] = make_int2(col[e] | ((r & (ROWS_PER_BKT - 1)) << 20),
                              __float_as_int(vals[e]));
          lbid[p] = (unsigned char)b;
        }
      }
    }
  }
  __syncthreads();
  // phase 4: coalesced copy-out
  for (int i = t; i < cntE; i += 512) {
    int b = lbid[i];
    int off = i - lofs[b];
    int g = gbase[b] + off;
    if (g - b * SLOT_E < SLOT_E) tmp[g] = lbuf[i];
  }
}

// ---------------- per-bucket counting sort (scan fused) ----------------------
__global__ __launch_bounds__(512) void bucket_sort_kernel(
    const int* __restrict__ bcurf, const int2* __restrict__ tmp,
    int2* __restrict__ ce, int* __restrict__ row_ptr, int n) {
  __shared__ int binc[MAX_BKT];
  __shared__ int bcnt_s[MAX_BKT];
  __shared__ int rcnt[ROWS_PER_BKT];
  __shared__ int rpos[ROWS_PER_BKT];
  __shared__ int sc[ROWS_PER_BKT];
  const int t = threadIdx.x;
  const int b = blockIdx.x;
  if (t < MAX_BKT) { int c = bcurf[t]; bcnt_s[t] = c; binc[t] = c; }
  __syncthreads();
  for (int off = 1; off < MAX_BKT; off <<= 1) {
    int u = (t < MAX_BKT && t >= off) ? binc[t - off] : 0;
    __syncthreads();
    if (t < MAX_BKT) binc[t] += u;
    __syncthreads();
  }
  const int start = binc[b] - bcnt_s[b];
  const int len   = bcnt_s[b];
  if (b == gridDim.x - 1 && t == 0) row_ptr[n] = binc[MAX_BKT - 1];   // == nE
  const int2* ts = tmp + (size_t)b * SLOT_E;
  rcnt[t] = 0;
  __syncthreads();
  const int* keys = (const int*)ts;              // ts[i].x at index 2*i
  for (int i = t; i < len; i += 512)
    atomicAdd(&rcnt[((unsigned)keys[2 * i]) >> 20], 1);
  __syncthreads();
  sc[t] = rcnt[t];
  __syncthreads();
  for (int off = 1; off < ROWS_PER_BKT; off <<= 1) {
    int u = (t >= off) ? sc[t - off] : 0;
    __syncthreads();
    sc[t] += u;
    __syncthreads();
  }
  {
    int ex = sc[t] - rcnt[t];
    int gpos = start + ex;
    rpos[t] = gpos;
    int gr = b * ROWS_PER_BKT + t;
    if (gr < n) row_ptr[gr] = gpos;
  }
  __syncthreads();
  for (int i = t; i < len; i += 512) {
    int2 e = ts[i];
    int p = atomicAdd(&rpos[((unsigned)e.x) >> 20], 1);
    ce[p] = make_int2(e.x & 0xFFFFF, e.y);
  }
}

// ---------------- Linear1: coalesced sA staging + global-L1 W1T --------------
__global__ __launch_bounds__(256) void lin1_kernel(
    const float* __restrict__ emb, const float* __restrict__ deg,
    const float* __restrict__ seed, const short* __restrict__ w1t,
    const float* __restrict__ b1, unsigned char* __restrict__ out, int n) {
  __shared__ short sA[64 * SASTR];
  const int t = threadIdx.x;
  const int base = blockIdx.x * 64;

  for (int idx = t; idx < 64 * 32; idx += 256) {
    int nn = idx >> 5, k4 = idx & 31;
    int node = base + nn;
    short4 wv;
    if (node < n) {
      float4 v = ((const float4*)emb)[(size_t)node * 32 + k4];
      wv = make_short4(f2bfs(v.x), f2bfs(v.y), f2bfs(v.z), f2bfs(v.w));
    } else {
      wv = make_short4(0, 0, 0, 0);
    }
    *(short4*)&sA[nn * SASTR + 4 * k4] = wv;
  }
  for (int idx = t; idx < 64 * 32; idx += 256) {
    int nn = idx >> 5, kk = idx & 31;
    int node = base + nn;
    float v = 0.f;
    if (node < n) {
      if (kk == 0) v = deg[node];
      else if (kk == 1) v = seed[node];
    }
    sA[nn * SASTR + 128 + kk] = f2bfs(v);
  }
  __syncthreads();

  const int lane = t & 63, w = t >> 6;
  const int nl = lane & 15, q = lane >> 4;
  const short* pA = &sA[(w * 16 + nl) * SASTR + q * 8];
  const short* pB = w1t + nl * W1TS + q * 8;
  const float bias0 = b1[nl], bias1 = b1[16 + nl],
              bias2 = b1[32 + nl], bias3 = b1[48 + nl];

  fx4 ac0 = {0.f, 0.f, 0.f, 0.f}, ac1 = ac0, ac2 = ac0, ac3 = ac0;
#pragma unroll
  for (int kt = 0; kt < 5; ++kt) {
    bf16x8 a   = *(const bf16x8*)(pA + kt * 32);
    bf16x8 b0  = *(const bf16x8*)(pB + kt * 32);
    bf16x8 b1v = *(const bf16x8*)(pB + 16 * W1TS + kt * 32);
    bf16x8 b2v = *(const bf16x8*)(pB + 32 * W1TS + kt * 32);
    bf16x8 b3v = *(const bf16x8*)(pB + 48 * W1TS + kt * 32);
    ac0 = __builtin_amdgcn_mfma_f32_16x16x32_bf16(a, b0,  ac0, 0, 0, 0);
    ac1 = __builtin_amdgcn_mfma_f32_16x16x32_bf16(a, b1v, ac1, 0, 0, 0);
    ac2 = __builtin_amdgcn_mfma_f32_16x16x32_bf16(a, b2v, ac2, 0, 0, 0);
    ac3 = __builtin_amdgcn_mfma_f32_16x16x32_bf16(a, b3v, ac3, 0, 0, 0);
  }
#pragma unroll
  for (int r = 0; r < 4; ++r) {
    int node = base + w * 16 + q * 4 + r;
    if (node < n) {
      unsigned char* o = out + ((size_t)node << 6);
      o[nl]      = f2fp8(ac0[r] + bias0);
      o[16 + nl] = f2fp8(ac1[r] + bias1);
      o[32 + nl] = f2fp8(ac2[r] + bias2);
      o[48 + nl] = f2fp8(ac3[r] + bias3);
    }
  }
}

// ==== fp8 gather: one ROW per 8-lane subgroup (no cross-subgroup reduce) ====
#define GLD(ev, u)                                                            \
  const uint2 u = *(const uint2*)(xp + (((size_t)(unsigned)(ev)) << 6) + 8 * fl);
#define GMAD(ev, u)                                                           \
  {                                                                           \
    const float v = __int_as_float((int)((ev) >> 32));                        \
    const fx2 v2 = {v, v};                                                    \
    a0 += v2 * __builtin_amdgcn_cvt_pk_f32_fp8(u.x, false);                   \
    a1 += v2 * __builtin_amdgcn_cvt_pk_f32_fp8(u.x, true);                    \
    a2 += v2 * __builtin_amdgcn_cvt_pk_f32_fp8(u.y, false);                   \
    a3 += v2 * __builtin_amdgcn_cvt_pk_f32_fp8(u.y, true);                    \
  }
#define GMAD_P(ev, u, ok)                                                     \
  {                                                                           \
    const float v = (ok) ? __int_as_float((int)((ev) >> 32)) : 0.f;           \
    const fx2 v2 = {v, v};                                                    \
    a0 += v2 * __builtin_amdgcn_cvt_pk_f32_fp8(u.x, false);                   \
    a1 += v2 * __builtin_amdgcn_cvt_pk_f32_fp8(u.x, true);                    \
    a2 += v2 * __builtin_amdgcn_cvt_pk_f32_fp8(u.y, false);                   \
    a3 += v2 * __builtin_amdgcn_cvt_pk_f32_fp8(u.y, true);                    \
  }

#define SPMM_STAGE_EDGES                                                      \
  const unsigned long long* cep = (const unsigned long long*)ce;              \
  const int r0blk = blockIdx.x * RPB;                                         \
  const int bstartE = row_ptr[r0blk];                                         \
  const int bendE = row_ptr[(r0blk + RPB < n) ? (r0blk + RPB) : n];           \
  const int cnt = min(bendE - bstartE, ECAP);                                 \
  for (int ii = threadIdx.x; ii < cnt; ii += 256)                             \
    eb[ii] = __builtin_nontemporal_load(cep + bstartE + ii);                  \
  __syncthreads();

// per-subgroup gather of row r into a0..a3 (8 f32 in lane fl)
#define SPMM_GATHER_BODY                                                      \
  const int i0r = row_ptr[r];                                                 \
  const int endr = row_ptr[r + 1];                                            \
  const int lend = endr - bstartE;                                            \
  if (lend <= cnt) {                                                          \
    int i = i0r - bstartE;                                                    \
    for (; i + 4 <= lend; i += 4) {                                           \
      unsigned long long e0 = eb[i];                                          \
      unsigned long long e1 = eb[i + 1];                                      \
      unsigned long long e2 = eb[i + 2];                                      \
      unsigned long long e3 = eb[i + 3];                                      \
      GLD(e0, u0); GLD(e1, u1); GLD(e2, u2); GLD(e3, u3);                     \
      GMAD(e0, u0); GMAD(e1, u1); GMAD(e2, u2); GMAD(e3, u3);                 \
    }                                                                         \
    if (i < lend) {                                                           \
      const int last = lend - 1;                                              \
      bool k1 = i + 1 < lend, k2 = i + 2 < lend, k3 = i + 3 < lend;           \
      unsigned long long e0 = eb[i];                                          \
      unsigned long long e1 = eb[k1 ? i + 1 : last];                          \
      unsigned long long e2 = eb[k2 ? i + 2 : last];                          \
      unsigned long long e3 = eb[k3 ? i + 3 : last];                          \
      GLD(e0, u0); GLD(e1, u1); GLD(e2, u2); GLD(e3, u3);                     \
      GMAD(e0, u0); GMAD_P(e1, u1, k1);                                       \
      GMAD_P(e2, u2, k2); GMAD_P(e3, u3, k3);                                 \
    }                                                                         \
  } else {                                                                    \
    int i = i0r;                                                              \
    for (; i + 4 <= endr; i += 4) {                                           \
      unsigned long long e0 = __builtin_nontemporal_load(cep + i);            \
      unsigned long long e1 = __builtin_nontemporal_load(cep + i + 1);        \
      unsigned long long e2 = __builtin_nontemporal_load(cep + i + 2);        \
      unsigned long long e3 = __builtin_nontemporal_load(cep + i + 3);        \
      GLD(e0, u0); GLD(e1, u1); GLD(e2, u2); GLD(e3, u3);                     \
      GMAD(e0, u0); GMAD(e1, u1); GMAD(e2, u2); GMAD(e3, u3);                 \
    }                                                                         \
    if (i < endr) {                                                           \
      const int last = endr - 1;                                              \
      bool k1 = i + 1 < endr, k2 = i + 2 < endr, k3 = i + 3 < endr;           \
      unsigned long long e0 = cep[i];                                         \
      unsigned long long e1 = cep[k1 ? i + 1 : last];                         \
      unsigned long long e2 = cep[k2 ? i + 2 : last];                         \
      unsigned long long e3 = cep[k3 ? i + 3 : last];                         \
      GLD(e0, u0); GLD(e1, u1); GLD(e2, u2); GLD(e3, u3);                     \
      GMAD(e0, u0); GMAD_P(e1, u1, k1);                                       \
      GMAD_P(e2, u2, k2); GMAD_P(e3, u3, k3);                                 \
    }                                                                         \
  }

// ---------------- SpMM1 + ReLU + FUSED Linear2 -> xb -------------------------
// Per block: gather 32 rows (one per 8-lane subgroup), ReLU, pack fp8 into a
// 2.3KB LDS tile; then lin2 on those 32 rows via MFMA (wave w: rows
// (w&1)*16.., cols (w>>1)*32..) reading B-fragments from L1-resident w2t.
// Removes the y HBM round-trip (12.8MB) and one kernel launch.
__global__ __launch_bounds__(256) void spmm1_lin2_kernel(
    const int* __restrict__ row_ptr, const int2* __restrict__ ce,
    const unsigned char* __restrict__ x, const short* __restrict__ w2t,
    const float* __restrict__ b2, unsigned char* __restrict__ xout, int n) {
  __shared__ unsigned long long eb[ECAP];
  __shared__ unsigned char sY[RPB * SYSTR];    // 32 rows x 64B (72B stride)
  const int fl = threadIdx.x & 7;
  const int sg = threadIdx.x >> 3;             // local row 0..31
  const int r = blockIdx.x * RPB + sg;
  const unsigned char* xp = x;
  SPMM_STAGE_EDGES
  int lo = 0, hi = 0;
  if (r < n) {
    fx2 a0 = {0.f, 0.f}, a1 = a0, a2 = a0, a3 = a0;
    SPMM_GATHER_BODY
    lo = pk_fp8x4(fmaxf(a0.x, 0.f), fmaxf(a0.y, 0.f),
                  fmaxf(a1.x, 0.f), fmaxf(a1.y, 0.f));
    hi = pk_fp8x4(fmaxf(a2.x, 0.f), fmaxf(a2.y, 0.f),
                  fmaxf(a3.x, 0.f), fmaxf(a3.y, 0.f));
  }
  *(int2*)&sY[sg * SYSTR + 8 * fl] = make_int2(lo, hi);
  __syncthreads();

  // fused lin2: 32 nodes x 64 cols, 4 waves each doing a 16x32 output tile
  const int lane = threadIdx.x & 63, w = threadIdx.x >> 6;
  const int nl = lane & 15, q = lane >> 4;
  const int rowg = (w & 1) * 16;               // node-row offset in block
  const int colg = (w >> 1) * 32;              // output-col offset
  const unsigned char* pY = &sY[(rowg + nl) * SYSTR + q * 8];
  const short* pB = w2t + (colg + nl) * 64 + q * 8;
  const float bias0 = b2[colg + nl], bias1 = b2[colg + 16 + nl];
  fx4 ac0 = {0.f, 0.f, 0.f, 0.f}, ac1 = ac0;
#pragma unroll
  for (int kt = 0; kt < 2; ++kt) {
    uint2 u8 = *(const uint2*)(pY + kt * 32);
    fx2 f0 = __builtin_amdgcn_cvt_pk_f32_fp8(u8.x, false);
    fx2 f1 = __builtin_amdgcn_cvt_pk_f32_fp8(u8.x, true);
    fx2 f2 = __builtin_amdgcn_cvt_pk_f32_fp8(u8.y, false);
    fx2 f3 = __builtin_amdgcn_cvt_pk_f32_fp8(u8.y, true);
    bf16x8 a;
    a[0] = f2bfs(f0.x); a[1] = f2bfs(f0.y); a[2] = f2bfs(f1.x); a[3] = f2bfs(f1.y);
    a[4] = f2bfs(f2.x); a[5] = f2bfs(f2.y); a[6] = f2bfs(f3.x); a[7] = f2bfs(f3.y);
    bf16x8 b0  = *(const bf16x8*)(pB + kt * 32);
    bf16x8 b1v = *(const bf16x8*)(pB + 16 * 64 + kt * 32);
    ac0 = __builtin_amdgcn_mfma_f32_16x16x32_bf16(a, b0,  ac0, 0, 0, 0);
    ac1 = __builtin_amdgcn_mfma_f32_16x16x32_bf16(a, b1v, ac1, 0, 0, 0);
  }
#pragma unroll
  for (int r2 = 0; r2 < 4; ++r2) {
    int node = blockIdx.x * RPB + rowg + q * 4 + r2;
    if (node < n) {
      unsigned char* o = xout + ((size_t)node << 6);
      o[colg + nl]      = f2fp8(ac0[r2] + bias0);
      o[colg + 16 + nl] = f2fp8(ac1[r2] + bias1);
    }
  }
}

// ---------------- SpMM2 (fp8 gather) + ReLU + Wout-dot -> block partial ------
__global__ __launch_bounds__(256) void spmm2_fused_kernel(
    const int* __restrict__ row_ptr, const int2* __restrict__ ce,
    const unsigned char* __restrict__ x, const float* __restrict__ Wout,
    float* __restrict__ partials, int n) {
  __shared__ unsigned long long eb[ECAP];
  const int fl = threadIdx.x & 7;
  const int r = blockIdx.x * RPB + (threadIdx.x >> 3);
  const unsigned char* xp = x;
  SPMM_STAGE_EDGES
  float wpart = 0.f;
  if (r < n) {
    fx2 a0 = {0.f, 0.f}, a1 = a0, a2 = a0, a3 = a0;
    SPMM_GATHER_BODY
    const float4 wv0 = ((const float4*)Wout)[2 * fl];
    const float4 wv1 = ((const float4*)Wout)[2 * fl + 1];
    wpart = fmaxf(a0.x, 0.f) * wv0.x + fmaxf(a0.y, 0.f) * wv0.y
          + fmaxf(a1.x, 0.f) * wv0.z + fmaxf(a1.y, 0.f) * wv0.w
          + fmaxf(a2.x, 0.f) * wv1.x + fmaxf(a2.y, 0.f) * wv1.y
          + fmaxf(a3.x, 0.f) * wv1.z + fmaxf(a3.y, 0.f) * wv1.w;
  }
  // full-wave reduce (sums all 8 subgroups' rows in this wave)
  for (int off = 32; off; off >>= 1) wpart += __shfl_down(wpart, off, 64);
  __shared__ float part[4];
  const int lane = threadIdx.x & 63;
  if (lane == 0) part[threadIdx.x >> 6] = wpart;
  __syncthreads();
  if (threadIdx.x == 0)
    partials[blockIdx.x] = part[0] + part[1] + part[2] + part[3];
}

// ---------------- final: sum partials (1 block, float4) ----------------------
__global__ __launch_bounds__(1024) void reduce_kernel(
    const float* __restrict__ partials, const float* __restrict__ bout,
    float* __restrict__ out, int m) {
  const int t = threadIdx.x;
  float s = 0.f;
  const int m4 = m >> 2;
  for (int i = t; i < m4; i += 1024) {
    float4 v = ((const float4*)partials)[i];
    s += v.x + v.y + v.z + v.w;
  }
  if (t < (m & 3)) s += partials[(m & ~3) + t];
  for (int off = 32; off; off >>= 1) s += __shfl_down(s, off, 64);
  __shared__ float wsum[16];
  if ((t & 63) == 0) wsum[t >> 6] = s;
  __syncthreads();
  if (t == 0) {
    float tot = bout[0];
    for (int w = 0; w < 16; ++w) tot += wsum[w];
    out[0] = tot;
  }
}

extern "C" void kernel_launch(void* const* d_in, const int* in_sizes, int n_in,
                              void* d_out, int out_size, void* d_ws, size_t ws_size,
                              hipStream_t stream) {
  const float* emb  = (const float*)d_in[0];
  const float* deg  = (const float*)d_in[1];
  const float* seed = (const float*)d_in[2];
  const int*   row  = (const int*)d_in[3];
  const int*   col  = (const int*)d_in[4];
  const float* vals = (const float*)d_in[5];
  const float* W1   = (const float*)d_in[6];
  const float* b1   = (const float*)d_in[7];
  const float* W2   = (const float*)d_in[8];
  const float* b2   = (const float*)d_in[9];
  const float* Wout = (const float*)d_in[10];
  const float* bout = (const float*)d_in[11];
  float* out = (float*)d_out;

  const int n  = in_sizes[0] / IN_EMB;   // 100000
  const int nE = in_sizes[3];            // 3200000
  const int nbkt = (n + ROWS_PER_BKT - 1) / ROWS_PER_BKT;   // 196

  const int lin_blocks  = (n + 63) / 64;        // 1563 (64 nodes/block)
  const int row_blocks  = (n + RPB - 1) / RPB;  // 3125 (32 rows/block)
  const int part_blocks = (nE + PART_CHUNK - 1) / PART_CHUNK;  // 782

  // ---- workspace layout ----
  char* ws = (char*)d_ws;
  int2* ce   = (int2*)ws;  ws += (size_t)nE * sizeof(int2);             // live to end
  char* tmpb = ws;
  int2* tmp  = (int2*)ws;  ws += (size_t)nbkt * SLOT_E * sizeof(int2);  // dead after sort
  unsigned char* xb = (unsigned char*)ws;  ws += ((size_t)n * HID + 255) & ~255ULL;  // fp8
  int* row_ptr = (int*)ws; ws += ((size_t)(n + 1) * 4 + 255) & ~255ULL;
  int* bcur    = (int*)ws; ws += ((size_t)MAX_BKT * 4 + 255) & ~255ULL;
  short* w1t   = (short*)ws; ws += ((size_t)64 * W1TS * 2 + 255) & ~255ULL;
  short* w2t   = (short*)ws; ws += ((size_t)64 * 64 * 2 + 255) & ~255ULL;
  float* partials = (float*)ws;                                         // row_blocks floats
  // alias into dead tmp region: xa (6.4MB), used only after bucket_sort.
  unsigned char* xa = (unsigned char*)tmpb;

  // ---- weight prep (also zeroes bcur) + CSR build ----
  wprep_kernel<<<3, 256, 0, stream>>>(W1, W2, w1t, w2t, bcur);
  partition_kernel<<<part_blocks, 512, 0, stream>>>(row, col, vals, bcur, tmp, nE);
  bucket_sort_kernel<<<nbkt, 512, 0, stream>>>(bcur, tmp, ce, row_ptr, n);

  // ---- network: lin1 -> (spmm1 + lin2 fused) -> (spmm2 + Wout fused) ----
  lin1_kernel<<<lin_blocks, 256, 0, stream>>>(emb, deg, seed, w1t, b1, xa, n);
  spmm1_lin2_kernel<<<row_blocks, 256, 0, stream>>>(row_ptr, ce, xa, w2t, b2, xb, n);
  spmm2_fused_kernel<<<row_blocks, 256, 0, stream>>>(row_ptr, ce, xb, Wout, partials, n);
  reduce_kernel<<<1, 1024, 0, stream>>>(partials, bout, out, row_blocks);
}

// Round 14
// 283.108 us; speedup vs baseline: 1.0332x; 1.0114x over previous
//
#include <hip/hip_runtime.h>
#include <hip/hip_bf16.h>

#define HID 64
#define IN_EMB 128
#define IN_DIM 130
#define ROWS_PER_BKT 512      // coarse buckets: 100000/512 -> 196 buckets
#define LOG_RPB 9
#define MAX_BKT 256           // >= nbkt (196); bcur allocated/zeroed to MAX_BKT
#define PART_CHUNK 4096       // edges per partition block (782 blocks)
#define SLOT_E 18432          // fixed tmp slot per bucket (mean 16384, sd 128 -> 16 sigma)
#define W1TS 160              // W1T row stride (k entries, zero-padded past 130)
#define SASTR 168             // lin1 sA row stride (shorts; 2-way banks, free)
#define SYSTR 72              // fused-lin2 sY row stride (bytes)
#define RPB 32                // rows per spmm block (one row per 8-lane subgroup)
#define ECAP 2048             // staged edges per spmm block (16KB LDS); avg 1024
#define LIN1_NPB 128          // lin1 nodes per block (512 threads, 8 waves)
#define SMEM_BYTES 43008      // union: lin1 sA (43008) vs partition (~41988)

typedef __hip_bfloat16 bf16;
typedef __attribute__((ext_vector_type(8))) short bf16x8;
typedef __attribute__((ext_vector_type(4))) float fx4;
typedef __attribute__((ext_vector_type(2))) float fx2;

__device__ __forceinline__ short f2bfs(float f) {
  __hip_bfloat16 h = __float2bfloat16(f);
  return *(reinterpret_cast<short*>(&h));
}
// pack 4 floats -> 4 fp8 e4m3 bytes (HW cvt)
__device__ __forceinline__ int pk_fp8x4(float a, float b, float c, float d) {
  int v = __builtin_amdgcn_cvt_pk_fp8_f32(a, b, 0, false);
  v = __builtin_amdgcn_cvt_pk_fp8_f32(c, d, v, true);
  return v;
}
__device__ __forceinline__ unsigned char f2fp8(float x) {
  return (unsigned char)(__builtin_amdgcn_cvt_pk_fp8_f32(x, x, 0, false) & 0xFF);
}

// ---------------- weight transpose prep + bcur zero --------------------------
__global__ __launch_bounds__(256) void wprep_kernel(
    const float* __restrict__ W1, const float* __restrict__ W2,
    short* __restrict__ w1t, short* __restrict__ w2t, int* __restrict__ bcur) {
  const int t = threadIdx.x;
  if (blockIdx.x == 0) {
    for (int idx = t; idx < 64 * W1TS; idx += 256) {
      int c = idx / W1TS, k = idx % W1TS;
      w1t[idx] = f2bfs((k < IN_DIM) ? W1[k * HID + c] : 0.f);
    }
  } else if (blockIdx.x == 1) {
    for (int idx = t; idx < 64 * 64; idx += 256) {
      int c = idx >> 6, k = idx & 63;
      w2t[idx] = f2bfs(W2[k * HID + c]);
    }
  } else {
    if (t < MAX_BKT) bcur[t] = 0;
  }
}

// ---------------- FUSED: edge partition (blocks < pb) | lin1 (blocks >= pb) --
// Independent workloads co-scheduled in ONE launch so the latency-bound
// partition and lin1 hide each other's stalls. LDS is a union (43KB).
__global__ __launch_bounds__(512) void build_lin1_kernel(
    const int* __restrict__ row, const int* __restrict__ col,
    const float* __restrict__ vals, int* __restrict__ bcur,
    int2* __restrict__ tmp, int nE,
    const float* __restrict__ emb, const float* __restrict__ deg,
    const float* __restrict__ seed, const short* __restrict__ w1t,
    const float* __restrict__ b1, unsigned char* __restrict__ xa,
    int n, int part_blocks) {
  __shared__ __align__(16) char smem[SMEM_BYTES];
  const int t = threadIdx.x;

  if ((int)blockIdx.x < part_blocks) {
    // ================= partition branch (LDS-reordered scatter) =============
    int2* lbuf = (int2*)smem;                          // 32768 B
    unsigned char* lbid = (unsigned char*)(smem + 32768);  // 4096 B
    int* h     = (int*)(smem + 36864);
    int* sc    = (int*)(smem + 37888);
    int* lofs  = (int*)(smem + 38912);                 // 257 ints
    int* lcur  = (int*)(smem + 39952);
    int* gbase = (int*)(smem + 40976);
    const int base = blockIdx.x * PART_CHUNK;
    const int cntE = min(PART_CHUNK, nE - base);

    if (t < MAX_BKT) h[t] = 0;
    __syncthreads();
    for (int kk = t; kk < PART_CHUNK / 4; kk += 512) {
      int e0 = base + kk * 4;
      if (e0 + 3 < nE) {
        int4 r4 = ((const int4*)row)[(base >> 2) + kk];
        atomicAdd(&h[r4.x >> LOG_RPB], 1);
        atomicAdd(&h[r4.y >> LOG_RPB], 1);
        atomicAdd(&h[r4.z >> LOG_RPB], 1);
        atomicAdd(&h[r4.w >> LOG_RPB], 1);
      } else {
        for (int j = 0; j < 4; ++j) {
          int e = e0 + j;
          if (e < nE) atomicAdd(&h[row[e] >> LOG_RPB], 1);
        }
      }
    }
    __syncthreads();
    if (t < MAX_BKT) sc[t] = h[t];
    __syncthreads();
    for (int off = 1; off < MAX_BKT; off <<= 1) {
      int u = (t < MAX_BKT && t >= off) ? sc[t - off] : 0;
      __syncthreads();
      if (t < MAX_BKT) sc[t] += u;
      __syncthreads();
    }
    if (t < MAX_BKT) {
      int ex = sc[t] - h[t];
      lofs[t] = ex;
      lcur[t] = ex;
      if (h[t] > 0) gbase[t] = t * SLOT_E + atomicAdd(&bcur[t], h[t]);
    }
    if (t == MAX_BKT - 1) lofs[MAX_BKT] = sc[t];   // == cntE
    __syncthreads();
    for (int kk = t; kk < PART_CHUNK / 4; kk += 512) {
      int e0 = base + kk * 4;
      if (e0 + 3 < nE) {
        int4 r4 = ((const int4*)row)[(base >> 2) + kk];
        int4 c4 = ((const int4*)col)[(base >> 2) + kk];
        float4 v4 = ((const float4*)vals)[(base >> 2) + kk];
        int rr[4] = {r4.x, r4.y, r4.z, r4.w};
        int cc[4] = {c4.x, c4.y, c4.z, c4.w};
        float vv[4] = {v4.x, v4.y, v4.z, v4.w};
#pragma unroll
        for (int j = 0; j < 4; ++j) {
          int b = rr[j] >> LOG_RPB;
          int p = atomicAdd(&lcur[b], 1);
          lbuf[p] = make_int2(cc[j] | ((rr[j] & (ROWS_PER_BKT - 1)) << 20),
                              __float_as_int(vv[j]));
          lbid[p] = (unsigned char)b;
        }
      } else {
        for (int j = 0; j < 4; ++j) {
          int e = e0 + j;
          if (e < nE) {
            int r = row[e];
            int b = r >> LOG_RPB;
            int p = atomicAdd(&lcur[b], 1);
            lbuf[p] = make_int2(col[e] | ((r & (ROWS_PER_BKT - 1)) << 20),
                                __float_as_int(vals[e]));
            lbid[p] = (unsigned char)b;
          }
        }
      }
    }
    __syncthreads();
    for (int i = t; i < cntE; i += 512) {
      int b = lbid[i];
      int off = i - lofs[b];
      int g = gbase[b] + off;
      if (g - b * SLOT_E < SLOT_E) tmp[g] = lbuf[i];
    }
  } else {
    // ================= lin1 branch: 128 nodes, 8 waves ======================
    short* sA = (short*)smem;                          // 128 x SASTR shorts
    const int base = (blockIdx.x - part_blocks) * LIN1_NPB;

    for (int idx = t; idx < LIN1_NPB * 32; idx += 512) {
      int nn = idx >> 5, k4 = idx & 31;
      int node = base + nn;
      short4 wv;
      if (node < n) {
        float4 v = ((const float4*)emb)[(size_t)node * 32 + k4];
        wv = make_short4(f2bfs(v.x), f2bfs(v.y), f2bfs(v.z), f2bfs(v.w));
      } else {
        wv = make_short4(0, 0, 0, 0);
      }
      *(short4*)&sA[nn * SASTR + 4 * k4] = wv;
    }
    for (int idx = t; idx < LIN1_NPB * 32; idx += 512) {
      int nn = idx >> 5, kk = idx & 31;
      int node = base + nn;
      float v = 0.f;
      if (node < n) {
        if (kk == 0) v = deg[node];
        else if (kk == 1) v = seed[node];
      }
      sA[nn * SASTR + 128 + kk] = f2bfs(v);
    }
    __syncthreads();

    const int lane = t & 63, w = t >> 6;           // w in 0..7
    const int nl = lane & 15, q = lane >> 4;
    const short* pA = &sA[(w * 16 + nl) * SASTR + q * 8];
    const short* pB = w1t + nl * W1TS + q * 8;
    const float bias0 = b1[nl], bias1 = b1[16 + nl],
                bias2 = b1[32 + nl], bias3 = b1[48 + nl];

    fx4 ac0 = {0.f, 0.f, 0.f, 0.f}, ac1 = ac0, ac2 = ac0, ac3 = ac0;
#pragma unroll
    for (int kt = 0; kt < 5; ++kt) {
      bf16x8 a   = *(const bf16x8*)(pA + kt * 32);
      bf16x8 b0  = *(const bf16x8*)(pB + kt * 32);
      bf16x8 b1v = *(const bf16x8*)(pB + 16 * W1TS + kt * 32);
      bf16x8 b2v = *(const bf16x8*)(pB + 32 * W1TS + kt * 32);
      bf16x8 b3v = *(const bf16x8*)(pB + 48 * W1TS + kt * 32);
      ac0 = __builtin_amdgcn_mfma_f32_16x16x32_bf16(a, b0,  ac0, 0, 0, 0);
      ac1 = __builtin_amdgcn_mfma_f32_16x16x32_bf16(a, b1v, ac1, 0, 0, 0);
      ac2 = __builtin_amdgcn_mfma_f32_16x16x32_bf16(a, b2v, ac2, 0, 0, 0);
      ac3 = __builtin_amdgcn_mfma_f32_16x16x32_bf16(a, b3v, ac3, 0, 0, 0);
    }
#pragma unroll
    for (int r = 0; r < 4; ++r) {
      int node = base + w * 16 + q * 4 + r;
      if (node < n) {
        unsigned char* o = xa + ((size_t)node << 6);
        o[nl]      = f2fp8(ac0[r] + bias0);
        o[16 + nl] = f2fp8(ac1[r] + bias1);
        o[32 + nl] = f2fp8(ac2[r] + bias2);
        o[48 + nl] = f2fp8(ac3[r] + bias3);
      }
    }
  }
}

// ---------------- per-bucket counting sort (scan fused) ----------------------
__global__ __launch_bounds__(512) void bucket_sort_kernel(
    const int* __restrict__ bcurf, const int2* __restrict__ tmp,
    int2* __restrict__ ce, int* __restrict__ row_ptr, int n) {
  __shared__ int binc[MAX_BKT];
  __shared__ int bcnt_s[MAX_BKT];
  __shared__ int rcnt[ROWS_PER_BKT];
  __shared__ int rpos[ROWS_PER_BKT];
  __shared__ int sc[ROWS_PER_BKT];
  const int t = threadIdx.x;
  const int b = blockIdx.x;
  if (t < MAX_BKT) { int c = bcurf[t]; bcnt_s[t] = c; binc[t] = c; }
  __syncthreads();
  for (int off = 1; off < MAX_BKT; off <<= 1) {
    int u = (t < MAX_BKT && t >= off) ? binc[t - off] : 0;
    __syncthreads();
    if (t < MAX_BKT) binc[t] += u;
    __syncthreads();
  }
  const int start = binc[b] - bcnt_s[b];
  const int len   = bcnt_s[b];
  if (b == gridDim.x - 1 && t == 0) row_ptr[n] = binc[MAX_BKT - 1];   // == nE
  const int2* ts = tmp + (size_t)b * SLOT_E;
  rcnt[t] = 0;
  __syncthreads();
  const int* keys = (const int*)ts;              // ts[i].x at index 2*i
  for (int i = t; i < len; i += 512)
    atomicAdd(&rcnt[((unsigned)keys[2 * i]) >> 20], 1);
  __syncthreads();
  sc[t] = rcnt[t];
  __syncthreads();
  for (int off = 1; off < ROWS_PER_BKT; off <<= 1) {
    int u = (t >= off) ? sc[t - off] : 0;
    __syncthreads();
    sc[t] += u;
    __syncthreads();
  }
  {
    int ex = sc[t] - rcnt[t];
    int gpos = start + ex;
    rpos[t] = gpos;
    int gr = b * ROWS_PER_BKT + t;
    if (gr < n) row_ptr[gr] = gpos;
  }
  __syncthreads();
  for (int i = t; i < len; i += 512) {
    int2 e = ts[i];
    int p = atomicAdd(&rpos[((unsigned)e.x) >> 20], 1);
    ce[p] = make_int2(e.x & 0xFFFFF, e.y);
  }
}

// ==== fp8 gather: one ROW per 8-lane subgroup (no cross-subgroup reduce) ====
#define GLD(ev, u)                                                            \
  const uint2 u = *(const uint2*)(xp + (((size_t)(unsigned)(ev)) << 6) + 8 * fl);
#define GMAD(ev, u)                                                           \
  {                                                                           \
    const float v = __int_as_float((int)((ev) >> 32));                        \
    const fx2 v2 = {v, v};                                                    \
    a0 += v2 * __builtin_amdgcn_cvt_pk_f32_fp8(u.x, false);                   \
    a1 += v2 * __builtin_amdgcn_cvt_pk_f32_fp8(u.x, true);                    \
    a2 += v2 * __builtin_amdgcn_cvt_pk_f32_fp8(u.y, false);                   \
    a3 += v2 * __builtin_amdgcn_cvt_pk_f32_fp8(u.y, true);                    \
  }
#define GMAD_P(ev, u, ok)                                                     \
  {                                                                           \
    const float v = (ok) ? __int_as_float((int)((ev) >> 32)) : 0.f;           \
    const fx2 v2 = {v, v};                                                    \
    a0 += v2 * __builtin_amdgcn_cvt_pk_f32_fp8(u.x, false);                   \
    a1 += v2 * __builtin_amdgcn_cvt_pk_f32_fp8(u.x, true);                    \
    a2 += v2 * __builtin_amdgcn_cvt_pk_f32_fp8(u.y, false);                   \
    a3 += v2 * __builtin_amdgcn_cvt_pk_f32_fp8(u.y, true);                    \
  }

#define SPMM_STAGE_EDGES                                                      \
  const unsigned long long* cep = (const unsigned long long*)ce;              \
  const int r0blk = blockIdx.x * RPB;                                         \
  const int bstartE = row_ptr[r0blk];                                         \
  const int bendE = row_ptr[(r0blk + RPB < n) ? (r0blk + RPB) : n];           \
  const int cnt = min(bendE - bstartE, ECAP);                                 \
  for (int ii = threadIdx.x; ii < cnt; ii += 256)                             \
    eb[ii] = __builtin_nontemporal_load(cep + bstartE + ii);                  \
  __syncthreads();

// per-subgroup gather of row r into a0..a3 (8 f32 in lane fl)
#define SPMM_GATHER_BODY                                                      \
  const int i0r = row_ptr[r];                                                 \
  const int endr = row_ptr[r + 1];                                            \
  const int lend = endr - bstartE;                                            \
  if (lend <= cnt) {                                                          \
    int i = i0r - bstartE;                                                    \
    for (; i + 4 <= lend; i += 4) {                                           \
      unsigned long long e0 = eb[i];                                          \
      unsigned long long e1 = eb[i + 1];                                      \
      unsigned long long e2 = eb[i + 2];                                      \
      unsigned long long e3 = eb[i + 3];                                      \
      GLD(e0, u0); GLD(e1, u1); GLD(e2, u2); GLD(e3, u3);                     \
      GMAD(e0, u0); GMAD(e1, u1); GMAD(e2, u2); GMAD(e3, u3);                 \
    }                                                                         \
    if (i < lend) {                                                           \
      const int last = lend - 1;                                              \
      bool k1 = i + 1 < lend, k2 = i + 2 < lend, k3 = i + 3 < lend;           \
      unsigned long long e0 = eb[i];                                          \
      unsigned long long e1 = eb[k1 ? i + 1 : last];                          \
      unsigned long long e2 = eb[k2 ? i + 2 : last];                          \
      unsigned long long e3 = eb[k3 ? i + 3 : last];                          \
      GLD(e0, u0); GLD(e1, u1); GLD(e2, u2); GLD(e3, u3);                     \
      GMAD(e0, u0); GMAD_P(e1, u1, k1);                                       \
      GMAD_P(e2, u2, k2); GMAD_P(e3, u3, k3);                                 \
    }                                                                         \
  } else {                                                                    \
    int i = i0r;                                                              \
    for (; i + 4 <= endr; i += 4) {                                           \
      unsigned long long e0 = __builtin_nontemporal_load(cep + i);            \
      unsigned long long e1 = __builtin_nontemporal_load(cep + i + 1);        \
      unsigned long long e2 = __builtin_nontemporal_load(cep + i + 2);        \
      unsigned long long e3 = __builtin_nontemporal_load(cep + i + 3);        \
      GLD(e0, u0); GLD(e1, u1); GLD(e2, u2); GLD(e3, u3);                     \
      GMAD(e0, u0); GMAD(e1, u1); GMAD(e2, u2); GMAD(e3, u3);                 \
    }                                                                         \
    if (i < endr) {                                                           \
      const int last = endr - 1;                                              \
      bool k1 = i + 1 < endr, k2 = i + 2 < endr, k3 = i + 3 < endr;           \
      unsigned long long e0 = cep[i];                                         \
      unsigned long long e1 = cep[k1 ? i + 1 : last];                         \
      unsigned long long e2 = cep[k2 ? i + 2 : last];                         \
      unsigned long long e3 = cep[k3 ? i + 3 : last];                         \
      GLD(e0, u0); GLD(e1, u1); GLD(e2, u2); GLD(e3, u3);                     \
      GMAD(e0, u0); GMAD_P(e1, u1, k1);                                       \
      GMAD_P(e2, u2, k2); GMAD_P(e3, u3, k3);                                 \
    }                                                                         \
  }

// ---------------- SpMM1 + ReLU + FUSED Linear2 -> xb -------------------------
__global__ __launch_bounds__(256) void spmm1_lin2_kernel(
    const int* __restrict__ row_ptr, const int2* __restrict__ ce,
    const unsigned char* __restrict__ x, const short* __restrict__ w2t,
    const float* __restrict__ b2, unsigned char* __restrict__ xout, int n) {
  __shared__ unsigned long long eb[ECAP];
  __shared__ unsigned char sY[RPB * SYSTR];    // 32 rows x 64B (72B stride)
  const int fl = threadIdx.x & 7;
  const int sg = threadIdx.x >> 3;             // local row 0..31
  const int r = blockIdx.x * RPB + sg;
  const unsigned char* xp = x;
  SPMM_STAGE_EDGES
  int lo = 0, hi = 0;
  if (r < n) {
    fx2 a0 = {0.f, 0.f}, a1 = a0, a2 = a0, a3 = a0;
    SPMM_GATHER_BODY
    lo = pk_fp8x4(fmaxf(a0.x, 0.f), fmaxf(a0.y, 0.f),
                  fmaxf(a1.x, 0.f), fmaxf(a1.y, 0.f));
    hi = pk_fp8x4(fmaxf(a2.x, 0.f), fmaxf(a2.y, 0.f),
                  fmaxf(a3.x, 0.f), fmaxf(a3.y, 0.f));
  }
  *(int2*)&sY[sg * SYSTR + 8 * fl] = make_int2(lo, hi);
  __syncthreads();

  // fused lin2: 32 nodes x 64 cols, 4 waves each doing a 16x32 output tile
  const int lane = threadIdx.x & 63, w = threadIdx.x >> 6;
  const int nl = lane & 15, q = lane >> 4;
  const int rowg = (w & 1) * 16;               // node-row offset in block
  const int colg = (w >> 1) * 32;              // output-col offset
  const unsigned char* pY = &sY[(rowg + nl) * SYSTR + q * 8];
  const short* pB = w2t + (colg + nl) * 64 + q * 8;
  const float bias0 = b2[colg + nl], bias1 = b2[colg + 16 + nl];
  fx4 ac0 = {0.f, 0.f, 0.f, 0.f}, ac1 = ac0;
#pragma unroll
  for (int kt = 0; kt < 2; ++kt) {
    uint2 u8 = *(const uint2*)(pY + kt * 32);
    fx2 f0 = __builtin_amdgcn_cvt_pk_f32_fp8(u8.x, false);
    fx2 f1 = __builtin_amdgcn_cvt_pk_f32_fp8(u8.x, true);
    fx2 f2 = __builtin_amdgcn_cvt_pk_f32_fp8(u8.y, false);
    fx2 f3 = __builtin_amdgcn_cvt_pk_f32_fp8(u8.y, true);
    bf16x8 a;
    a[0] = f2bfs(f0.x); a[1] = f2bfs(f0.y); a[2] = f2bfs(f1.x); a[3] = f2bfs(f1.y);
    a[4] = f2bfs(f2.x); a[5] = f2bfs(f2.y); a[6] = f2bfs(f3.x); a[7] = f2bfs(f3.y);
    bf16x8 b0  = *(const bf16x8*)(pB + kt * 32);
    bf16x8 b1v = *(const bf16x8*)(pB + 16 * 64 + kt * 32);
    ac0 = __builtin_amdgcn_mfma_f32_16x16x32_bf16(a, b0,  ac0, 0, 0, 0);
    ac1 = __builtin_amdgcn_mfma_f32_16x16x32_bf16(a, b1v, ac1, 0, 0, 0);
  }
#pragma unroll
  for (int r2 = 0; r2 < 4; ++r2) {
    int node = blockIdx.x * RPB + rowg + q * 4 + r2;
    if (node < n) {
      unsigned char* o = xout + ((size_t)node << 6);
      o[colg + nl]      = f2fp8(ac0[r2] + bias0);
      o[colg + 16 + nl] = f2fp8(ac1[r2] + bias1);
    }
  }
}

// ---------------- SpMM2 (fp8 gather) + ReLU + Wout-dot -> block partial ------
__global__ __launch_bounds__(256) void spmm2_fused_kernel(
    const int* __restrict__ row_ptr, const int2* __restrict__ ce,
    const unsigned char* __restrict__ x, const float* __restrict__ Wout,
    float* __restrict__ partials, int n) {
  __shared__ unsigned long long eb[ECAP];
  const int fl = threadIdx.x & 7;
  const int r = blockIdx.x * RPB + (threadIdx.x >> 3);
  const unsigned char* xp = x;
  SPMM_STAGE_EDGES
  float wpart = 0.f;
  if (r < n) {
    fx2 a0 = {0.f, 0.f}, a1 = a0, a2 = a0, a3 = a0;
    SPMM_GATHER_BODY
    const float4 wv0 = ((const float4*)Wout)[2 * fl];
    const float4 wv1 = ((const float4*)Wout)[2 * fl + 1];
    wpart = fmaxf(a0.x, 0.f) * wv0.x + fmaxf(a0.y, 0.f) * wv0.y
          + fmaxf(a1.x, 0.f) * wv0.z + fmaxf(a1.y, 0.f) * wv0.w
          + fmaxf(a2.x, 0.f) * wv1.x + fmaxf(a2.y, 0.f) * wv1.y
          + fmaxf(a3.x, 0.f) * wv1.z + fmaxf(a3.y, 0.f) * wv1.w;
  }
  // full-wave reduce (sums all 8 subgroups' rows in this wave)
  for (int off = 32; off; off >>= 1) wpart += __shfl_down(wpart, off, 64);
  __shared__ float part[4];
  const int lane = threadIdx.x & 63;
  if (lane == 0) part[threadIdx.x >> 6] = wpart;
  __syncthreads();
  if (threadIdx.x == 0)
    partials[blockIdx.x] = part[0] + part[1] + part[2] + part[3];
}

// ---------------- final: sum partials (1 block, float4) ----------------------
__global__ __launch_bounds__(1024) void reduce_kernel(
    const float* __restrict__ partials, const float* __restrict__ bout,
    float* __restrict__ out, int m) {
  const int t = threadIdx.x;
  float s = 0.f;
  const int m4 = m >> 2;
  for (int i = t; i < m4; i += 1024) {
    float4 v = ((const float4*)partials)[i];
    s += v.x + v.y + v.z + v.w;
  }
  if (t < (m & 3)) s += partials[(m & ~3) + t];
  for (int off = 32; off; off >>= 1) s += __shfl_down(s, off, 64);
  __shared__ float wsum[16];
  if ((t & 63) == 0) wsum[t >> 6] = s;
  __syncthreads();
  if (t == 0) {
    float tot = bout[0];
    for (int w = 0; w < 16; ++w) tot += wsum[w];
    out[0] = tot;
  }
}

extern "C" void kernel_launch(void* const* d_in, const int* in_sizes, int n_in,
                              void* d_out, int out_size, void* d_ws, size_t ws_size,
                              hipStream_t stream) {
  const float* emb  = (const float*)d_in[0];
  const float* deg  = (const float*)d_in[1];
  const float* seed = (const float*)d_in[2];
  const int*   row  = (const int*)d_in[3];
  const int*   col  = (const int*)d_in[4];
  const float* vals = (const float*)d_in[5];
  const float* W1   = (const float*)d_in[6];
  const float* b1   = (const float*)d_in[7];
  const float* W2   = (const float*)d_in[8];
  const float* b2   = (const float*)d_in[9];
  const float* Wout = (const float*)d_in[10];
  const float* bout = (const float*)d_in[11];
  float* out = (float*)d_out;

  const int n  = in_sizes[0] / IN_EMB;   // 100000
  const int nE = in_sizes[3];            // 3200000
  const int nbkt = (n + ROWS_PER_BKT - 1) / ROWS_PER_BKT;   // 196

  const int lin1_blocks = (n + LIN1_NPB - 1) / LIN1_NPB;    // 782
  const int row_blocks  = (n + RPB - 1) / RPB;              // 3125
  const int part_blocks = (nE + PART_CHUNK - 1) / PART_CHUNK;  // 782

  // ---- workspace layout (xa NO LONGER aliases tmp: concurrent writes) ----
  char* ws = (char*)d_ws;
  int2* ce   = (int2*)ws;  ws += (size_t)nE * sizeof(int2);             // live to end
  char* tmpb = ws;
  int2* tmp  = (int2*)ws;  ws += (size_t)nbkt * SLOT_E * sizeof(int2);  // dead after sort
  unsigned char* xa = (unsigned char*)ws;  ws += ((size_t)n * HID + 255) & ~255ULL;
  unsigned char* xb = (unsigned char*)ws;  ws += ((size_t)n * HID + 255) & ~255ULL;
  int* row_ptr = (int*)ws; ws += ((size_t)(n + 1) * 4 + 255) & ~255ULL;
  int* bcur    = (int*)ws; ws += ((size_t)MAX_BKT * 4 + 255) & ~255ULL;
  short* w1t   = (short*)ws; ws += ((size_t)64 * W1TS * 2 + 255) & ~255ULL;
  short* w2t   = (short*)ws; ws += ((size_t)64 * 64 * 2 + 255) & ~255ULL;
  float* partials = (float*)ws;                                         // row_blocks floats
  (void)tmpb;

  // ---- wprep, then FUSED (partition | lin1) in one launch ----
  wprep_kernel<<<3, 256, 0, stream>>>(W1, W2, w1t, w2t, bcur);
  build_lin1_kernel<<<part_blocks + lin1_blocks, 512, 0, stream>>>(
      row, col, vals, bcur, tmp, nE,
      emb, deg, seed, w1t, b1, xa, n, part_blocks);
  bucket_sort_kernel<<<nbkt, 512, 0, stream>>>(bcur, tmp, ce, row_ptr, n);

  // ---- network: (spmm1 + lin2 fused) -> (spmm2 + Wout fused) -> reduce ----
  spmm1_lin2_kernel<<<row_blocks, 256, 0, stream>>>(row_ptr, ce, xa, w2t, b2, xb, n);
  spmm2_fused_kernel<<<row_blocks, 256, 0, stream>>>(row_ptr, ce, xb, Wout, partials, n);
  reduce_kernel<<<1, 1024, 0, stream>>>(partials, bout, out, row_blocks);
}